// Round 1
// baseline (396.705 us; speedup 1.0000x reference)
//
#include <hip/hip_runtime.h>

typedef __bf16 bf16_t;
typedef __bf16 bf16x8 __attribute__((ext_vector_type(8)));
typedef __bf16 bf16x4 __attribute__((ext_vector_type(4)));
typedef float  floatx4 __attribute__((ext_vector_type(4)));

#define D_MODEL 1024
#define S_LEN   2048
#define NHEAD   16
#define DK      64
#define BATCH   4
#define MROWS   (BATCH * S_LEN)   // 8192
// 1/sqrt(64) * log2(e): fold into Q so scores arrive in exp2 domain
#define QSCALE  0.18033688011112042f

__device__ __forceinline__ void load_lds16(const void* gsrc, void* ldst) {
  __builtin_amdgcn_global_load_lds(
      (const __attribute__((address_space(1))) void*)gsrc,
      (__attribute__((address_space(3))) void*)ldst, 16, 0, 0);
}

__device__ __forceinline__ unsigned pack_bf16(float a, float b) {
  union { bf16_t h[2]; unsigned u; } t;
  t.h[0] = (bf16_t)a; t.h[1] = (bf16_t)b;
  return t.u;
}

__device__ __forceinline__ float bperm_f(int addr, float v) {
  union { float f; int i; } in, out;
  in.f = v;
  out.i = __builtin_amdgcn_ds_bpermute(addr, in.i);
  return out.f;
}

// ---------------------------------------------------------------------------
// Fused weight transpose + fp32->bf16 for all 4 weights (z selects).
// wqt/wkt/wvt are contiguous -> form a [3072][1024] matrix for the QKV GEMM.
// ---------------------------------------------------------------------------
__global__ __launch_bounds__(256)
void transpose_w_kernel(const float* __restrict__ W0, const float* __restrict__ W1,
                        const float* __restrict__ W2, const float* __restrict__ W3,
                        bf16_t* __restrict__ T0, bf16_t* __restrict__ T1,
                        bf16_t* __restrict__ T2, bf16_t* __restrict__ T3)
{
  const int z = blockIdx.z;
  const float* W = z == 0 ? W0 : (z == 1 ? W1 : (z == 2 ? W2 : W3));
  bf16_t* Wt     = z == 0 ? T0 : (z == 1 ? T1 : (z == 2 ? T2 : T3));

  __shared__ float tile[64][65];
  const int x0 = blockIdx.x * 64;         // n
  const int y0 = blockIdx.y * 64;         // k
  const int tid = threadIdx.x;
  const int r = tid >> 4;
  const int c = (tid & 15) << 2;
#pragma unroll
  for (int p = 0; p < 4; p++) {
    floatx4 v = *(const floatx4*)&W[(size_t)(y0 + p * 16 + r) * D_MODEL + x0 + c];
    tile[p * 16 + r][c + 0] = v[0];
    tile[p * 16 + r][c + 1] = v[1];
    tile[p * 16 + r][c + 2] = v[2];
    tile[p * 16 + r][c + 3] = v[3];
  }
  __syncthreads();
#pragma unroll
  for (int p = 0; p < 4; p++) {
    int row = p * 16 + r;
    bf16x4 o;
    o[0] = (bf16_t)tile[c + 0][row];
    o[1] = (bf16_t)tile[c + 1][row];
    o[2] = (bf16_t)tile[c + 2][row];
    o[3] = (bf16_t)tile[c + 3][row];
    *(bf16x4*)&Wt[(size_t)(x0 + row) * D_MODEL + y0 + c] = o;
  }
}

// ---------------------------------------------------------------------------
// Fused QKV projection, DOUBLE-BUFFERED (2-phase) staging:
//   next K-tile's global_load_lds issued BEFORE current tile's compute,
//   one barrier per iteration -> HBM/L2 latency hides under ds_read+cvt+MFMA.
//   A (fp32) -> LDS raw via global_load_lds (16B chunks, XOR swizzle),
//     converted fp32->bf16 at fragment-read time.
//   W (bf16, Wcat [3072][1024]) -> LDS via global_load_lds (XOR swizzle).
// XCD-locality swizzle unchanged. LDS = 2*(16K + 8K) = 48KB -> 3 blocks/CU
// (equals previously measured residency, so no occupancy loss).
// ---------------------------------------------------------------------------
__global__ __launch_bounds__(256, 3)
void qkv_kernel(const float* __restrict__ Qi, const float* __restrict__ Ki,
                const float* __restrict__ Vi, const bf16_t* __restrict__ Wcat,
                const float* __restrict__ bq, const float* __restrict__ bk,
                const float* __restrict__ bv,
                bf16_t* __restrict__ qo, bf16_t* __restrict__ ko,
                bf16_t* __restrict__ vo)
{
  __shared__ float  Asf[2][128 * 32];  // fp32 A tiles, 16B-chunk XOR swizzle
  __shared__ bf16_t Bs[2][128 * 32];   // bf16 W tiles, XOR swizzle

  // ---- XCD-locality decode ----
  const int L = blockIdx.x + 24 * blockIdx.y;     // 0..1535
  const int j = (L >> 3) & 7;
  const int s = ((L >> 6) << 3) | (L & 7);        // stripe 0..191
  const int z = s >> 6;                           // projection
  const int n0g = (((z << 3) | j)) << 7;          // global n over 3072
  const int m0 = (s & 63) << 7;

  const float* A = z == 0 ? Qi : (z == 1 ? Ki : Vi);

  const int tid = threadIdx.x;
  const int lane = tid & 63;
  const int w = tid >> 6;
  const int l15 = lane & 15;
  const int quad = lane >> 4;
  const int wy = (w >> 1) << 6;
  const int wx = (w & 1) << 6;
  const int w64 = w << 6;

  floatx4 acc[4][4];
#pragma unroll
  for (int i = 0; i < 4; i++)
#pragma unroll
    for (int jj = 0; jj < 4; jj++)
#pragma unroll
      for (int r = 0; r < 4; r++) acc[i][jj][r] = 0.0f;

  auto stage = [&](int buf, int kt) {
    const int k0 = kt << 5;
    // W: 512 chunks of 8 bf16; slot -> (row=slot>>2, kc=(slot&3)^(row&3))
#pragma unroll
    for (int p = 0; p < 2; p++) {
      int slot = p * 256 + w64 + lane;
      int row = slot >> 2;
      int kc = (slot & 3) ^ (row & 3);
      load_lds16(&Wcat[(size_t)(n0g + row) * D_MODEL + k0 + (kc << 3)],
                 &Bs[buf][(size_t)(p * 256 + w64) << 3]);
    }
    // A: 1024 chunks of 4 fp32; slot -> (row=slot>>3, ca=(slot&7)^(row&7))
#pragma unroll
    for (int p = 0; p < 4; p++) {
      int sbase = (w << 8) + (p << 6);
      int slot = sbase + lane;
      int row = slot >> 3;
      int ca = (slot & 7) ^ (row & 7);
      load_lds16(&A[(size_t)(m0 + row) * D_MODEL + k0 + (ca << 2)],
                 &Asf[buf][(size_t)sbase << 2]);
    }
  };

  stage(0, 0);
  int cur = 0;

  for (int kt = 0; kt < 32; kt++) {
    __syncthreads();            // drains buf[cur]'s staging (+ prior ds_reads)
    if (kt + 1 < 32) stage(cur ^ 1, kt + 1);   // prefetch next tile (in flight
                                               // across the compute below)
    const float*  As_c = Asf[cur];
    const bf16_t* Bs_c = Bs[cur];

    bf16x8 af[4], bfv[4];
#pragma unroll
    for (int mi = 0; mi < 4; mi++) {
      const int m = wy + mi * 16 + l15;
      const int e = m & 7;
      floatx4 f0 = *(const floatx4*)&As_c[(m << 5) + ((((quad << 1))     ^ e) << 2)];
      floatx4 f1 = *(const floatx4*)&As_c[(m << 5) + ((((quad << 1) | 1) ^ e) << 2)];
      bf16x8 o;
      o[0] = (bf16_t)f0[0]; o[1] = (bf16_t)f0[1];
      o[2] = (bf16_t)f0[2]; o[3] = (bf16_t)f0[3];
      o[4] = (bf16_t)f1[0]; o[5] = (bf16_t)f1[1];
      o[6] = (bf16_t)f1[2]; o[7] = (bf16_t)f1[3];
      af[mi] = o;
    }
#pragma unroll
    for (int ni = 0; ni < 4; ni++) {
      int n = wx + ni * 16 + l15;
      bfv[ni] = *(const bf16x8*)&Bs_c[n * 32 + ((quad ^ (n & 3)) << 3)];
    }
#pragma unroll
    for (int mi = 0; mi < 4; mi++)
#pragma unroll
      for (int ni = 0; ni < 4; ni++)
        acc[mi][ni] = __builtin_amdgcn_mfma_f32_16x16x32_bf16(
            af[mi], bfv[ni], acc[mi][ni], 0, 0, 0);

    cur ^= 1;
  }

  const float* bias = z == 0 ? bq : (z == 1 ? bk : bv);
  bf16_t* outp      = z == 0 ? qo : (z == 1 ? ko : vo);
  const float scl   = (z == 0) ? QSCALE : 1.0f;
#pragma unroll
  for (int mi = 0; mi < 4; mi++) {
#pragma unroll
    for (int ni = 0; ni < 4; ni++) {
      const int nn = (n0g + wx + ni * 16 + l15) & (D_MODEL - 1);
      const float bvv = bias[nn];
      const int h = nn >> 6, d = nn & 63;
#pragma unroll
      for (int r = 0; r < 4; r++) {
        const int m = m0 + wy + mi * 16 + quad * 4 + r;
        const int b = m >> 11, srow = m & (S_LEN - 1);
        float v = (acc[mi][ni][r] + bvv) * scl;
        if (z < 2) {
          outp[((((size_t)(b * NHEAD + h) << 11) + srow) << 6) + d] = (bf16_t)v;
        } else {
          outp[((((size_t)(b * NHEAD + h) << 6) + d) << 11) + srow] = (bf16_t)v;
        }
      }
    }
  }
}

// ---------------------------------------------------------------------------
// Output GEMM: out = obuf(bf16) @ Wo + bo, fp32 out. DOUBLE-BUFFERED staging
// (same 2-phase pattern as qkv). LDS = 2*(8K+8K) = 32KB -> 5 blocks/CU.
// Same XCD-locality swizzle (8 x-blocks per A-stripe; 64 stripes).
// ---------------------------------------------------------------------------
__global__ __launch_bounds__(256, 4)
void out_gemm_kernel(const bf16_t* __restrict__ A, const bf16_t* __restrict__ Wt,
                     const float* __restrict__ bias, float* __restrict__ out)
{
  __shared__ bf16_t As[2][128 * 32];
  __shared__ bf16_t Bs[2][128 * 32];
  const int L = blockIdx.x + 8 * blockIdx.y;      // 0..511
  const int n0 = (((L >> 3) & 7)) << 7;
  const int m0 = ((((L >> 6) << 3) | (L & 7))) << 7;
  const int tid = threadIdx.x;
  const int lane = tid & 63;
  const int w = tid >> 6;
  const int l15 = lane & 15;
  const int quad = lane >> 4;
  const int wy = (w >> 1) << 6;
  const int wx = (w & 1) << 6;
  const int w64 = w << 6;

  floatx4 acc[4][4];
#pragma unroll
  for (int i = 0; i < 4; i++)
#pragma unroll
    for (int jj = 0; jj < 4; jj++)
#pragma unroll
      for (int r = 0; r < 4; r++) acc[i][jj][r] = 0.0f;

  auto stage = [&](int buf, int kt) {
    const int k0 = kt << 5;
#pragma unroll
    for (int p = 0; p < 2; p++) {
      int slot = p * 256 + w64 + lane;
      int row = slot >> 2;
      int kc = (slot & 3) ^ (row & 3);
      load_lds16(&A[(size_t)(m0 + row) * D_MODEL + k0 + (kc << 3)],
                 &As[buf][(size_t)(p * 256 + w64) << 3]);
      load_lds16(&Wt[(size_t)(n0 + row) * D_MODEL + k0 + (kc << 3)],
                 &Bs[buf][(size_t)(p * 256 + w64) << 3]);
    }
  };

  stage(0, 0);
  int cur = 0;

  for (int kt = 0; kt < 32; kt++) {
    __syncthreads();
    if (kt + 1 < 32) stage(cur ^ 1, kt + 1);
    const bf16_t* As_c = As[cur];
    const bf16_t* Bs_c = Bs[cur];

    bf16x8 af[4], bfv[4];
#pragma unroll
    for (int mi = 0; mi < 4; mi++) {
      int m = wy + mi * 16 + l15;
      af[mi] = *(const bf16x8*)&As_c[m * 32 + ((quad ^ (m & 3)) << 3)];
    }
#pragma unroll
    for (int ni = 0; ni < 4; ni++) {
      int n = wx + ni * 16 + l15;
      bfv[ni] = *(const bf16x8*)&Bs_c[n * 32 + ((quad ^ (n & 3)) << 3)];
    }
#pragma unroll
    for (int mi = 0; mi < 4; mi++)
#pragma unroll
      for (int ni = 0; ni < 4; ni++)
        acc[mi][ni] = __builtin_amdgcn_mfma_f32_16x16x32_bf16(
            af[mi], bfv[ni], acc[mi][ni], 0, 0, 0);

    cur ^= 1;
  }

#pragma unroll
  for (int mi = 0; mi < 4; mi++) {
#pragma unroll
    for (int ni = 0; ni < 4; ni++) {
      const int nbase = n0 + wx + ni * 16 + l15;
      const float bv = bias[nbase];
#pragma unroll
      for (int r = 0; r < 4; r++) {
        const int m = m0 + wy + mi * 16 + quad * 4 + r;
        out[((size_t)m << 10) + nbase] = acc[mi][ni][r] + bv;
      }
    }
  }
}

// ---------------------------------------------------------------------------
// Causal flash attention, S^T formulation, BALANCED pairing (r5-verified).
// (unchanged — already double-buffered)
// ---------------------------------------------------------------------------
__global__ __launch_bounds__(256, 4)
void attn_kernel(const bf16_t* __restrict__ qp, const bf16_t* __restrict__ kp,
                 const bf16_t* __restrict__ vtp, bf16_t* __restrict__ ob)
{
  __shared__ bf16_t Kt0[64 * 64];
  __shared__ bf16_t Kt1[64 * 64];
  __shared__ bf16_t Vt0[64 * 64];
  __shared__ bf16_t Vt1[64 * 64];

  const int pair = blockIdx.x;             // 0..15
  const int bh = blockIdx.y;               // 0..63
  const int tid = threadIdx.x;
  const int w = tid >> 6;
  const int lane = tid & 63;
  const int l15 = lane & 15;
  const int quad = lane >> 4;

  const bf16_t* Qh = qp + ((size_t)bh << 17);
  const bf16_t* Kh = kp + ((size_t)bh << 17);
  const bf16_t* Vh = vtp + ((size_t)bh << 17);   // [64][2048]
  const int b = bh >> 4, h = bh & 15;

  auto stage = [&](int k0s, bf16_t* dK, bf16_t* dV) {
#pragma unroll
    for (int p = 0; p < 2; p++) {
      const int sbase = (w << 7) + (p << 6);
      const int slot = sbase + lane;
      const int row = slot >> 3;
      const int c = (slot & 7) ^ (row & 7);
      load_lds16(&Kh[((size_t)(k0s + row) << 6) + (c << 3)], &dK[sbase << 3]);
      load_lds16(&Vh[((size_t)row << 11) + k0s + (c << 3)], &dV[sbase << 3]);
    }
  };

  int par = 0;   // global tile-counter parity: current buffer index

  auto phase = [&](int qt, bool prefetch_next_phase) {
    const int q0 = qt << 6;
    const int qbase = q0 + (w << 4);       // wave's 16 q-rows
    const int nkb = qt + 1;

    bf16x8 qf[2];
#pragma unroll
    for (int ks = 0; ks < 2; ks++)
      qf[ks] = *(const bf16x8*)&Qh[(size_t)(qbase + l15) * DK +
                                   ks * 32 + (quad << 3)];

    floatx4 acc_o[4];
    float m_i = -1e30f, l_i = 0.0f;
#pragma unroll
    for (int nd = 0; nd < 4; nd++)
#pragma unroll
      for (int r = 0; r < 4; r++) acc_o[nd][r] = 0.0f;

    for (int kb = 0; kb < nkb; kb++) {
      const int k0 = kb << 6;
      __syncthreads();   // drains this tile's gll (issued one body ago)

      const bf16_t* cK = par ? Kt1 : Kt0;
      const bf16_t* cV = par ? Vt1 : Vt0;
      bf16_t* nK = par ? Kt0 : Kt1;
      bf16_t* nV = par ? Vt0 : Vt1;

      if (kb + 1 < nkb)             stage((kb + 1) << 6, nK, nV);
      else if (prefetch_next_phase) stage(0, nK, nV);

      bf16x8 bk[2][4];
#pragma unroll
      for (int ks = 0; ks < 2; ks++)
#pragma unroll
        for (int ni = 0; ni < 4; ni++) {
          const int row = ni * 16 + l15;
          const int cp = ((ks << 2) + quad) ^ (row & 7);
          bk[ks][ni] = *(const bf16x8*)&cK[(row << 6) + (cp << 3)];
        }

      floatx4 st[4];
#pragma unroll
      for (int ni = 0; ni < 4; ni++)
#pragma unroll
        for (int r = 0; r < 4; r++) st[ni][r] = 0.0f;
#pragma unroll
      for (int ks = 0; ks < 2; ks++)
#pragma unroll
        for (int ni = 0; ni < 4; ni++)
          st[ni] = __builtin_amdgcn_mfma_f32_16x16x32_bf16(
              bk[ks][ni], qf[ks], st[ni], 0, 0, 0);

      if (k0 + 63 > qbase) {
        const int qrow = qbase + l15;
#pragma unroll
        for (int ni = 0; ni < 4; ni++) {
          const int keyb = k0 + ni * 16 + quad * 4;
#pragma unroll
          for (int r = 0; r < 4; r++)
            if (keyb + r > qrow) st[ni][r] = -1e30f;
        }
      }

      float v = st[0][0];
#pragma unroll
      for (int ni = 0; ni < 4; ni++)
#pragma unroll
        for (int r = 0; r < 4; r++) v = fmaxf(v, st[ni][r]);
      v = fmaxf(v, __shfl_xor(v, 16));
      v = fmaxf(v, __shfl_xor(v, 32));
      const float mn = fmaxf(m_i, v);
      const float alpha = __builtin_amdgcn_exp2f(m_i - mn);
      m_i = mn;

      unsigned pd[4][2];
      float ssum = 0.0f;
#pragma unroll
      for (int c = 0; c < 4; c++)
#pragma unroll
        for (int hh = 0; hh < 2; hh++) {
          float p0 = __builtin_amdgcn_exp2f(st[c][2 * hh]     - m_i);
          float p1 = __builtin_amdgcn_exp2f(st[c][2 * hh + 1] - m_i);
          ssum += p0 + p1;
          pd[c][hh] = pack_bf16(p0, p1);
        }
      ssum += __shfl_xor(ssum, 16);
      ssum += __shfl_xor(ssum, 32);
      l_i = l_i * alpha + ssum;

#pragma unroll
      for (int r = 0; r < 4; r++) {
        float ab = bperm_f((quad * 4 + r) << 2, alpha);
#pragma unroll
        for (int nd = 0; nd < 4; nd++) acc_o[nd][r] *= ab;
      }

      union AV { unsigned u[4]; bf16x8 v; };
      AV av[2];
#pragma unroll
      for (int ks = 0; ks < 2; ks++)
#pragma unroll
        for (int i = 0; i < 4; i++) {
          const int addr = ((((2 * quad + (i >> 1)) & 3) << 4) | l15) << 2;
          int lo = __builtin_amdgcn_ds_bpermute(addr, (int)pd[ks * 2][i & 1]);
          int hi = __builtin_amdgcn_ds_bpermute(addr, (int)pd[ks * 2 + 1][i & 1]);
          av[ks].u[i] = (unsigned)(quad >= 2 ? hi : lo);
        }

#pragma unroll
      for (int ks = 0; ks < 2; ks++) {
        bf16x8 bvv[4];
#pragma unroll
        for (int nd = 0; nd < 4; nd++) {
          const int row = nd * 16 + l15;
          const int cp = ((ks << 2) + quad) ^ (row & 7);
          bvv[nd] = *(const bf16x8*)&cV[(row << 6) + (cp << 3)];
        }
#pragma unroll
        for (int nd = 0; nd < 4; nd++)
          acc_o[nd] = __builtin_amdgcn_mfma_f32_16x16x32_bf16(
              av[ks].v, bvv[nd], acc_o[nd], 0, 0, 0);
      }

      par ^= 1;
    }

    const float inv = 1.0f / l_i;
#pragma unroll
    for (int r = 0; r < 4; r++) {
      const float linv = bperm_f((quad * 4 + r) << 2, inv);
      const int sRow = qbase + quad * 4 + r;
#pragma unroll
      for (int nd = 0; nd < 4; nd++) {
        const int d = nd * 16 + l15;
        ob[(((size_t)(b * S_LEN + sRow)) << 10) + h * 64 + d] =
            (bf16_t)(acc_o[nd][r] * linv);
      }
    }
  };

  stage(0, Kt0, Vt0);            // tile 0 of phase A into buffer 0
  phase(31 - pair, true);        // big tile first; prefetch B's tile 0 at seam
  phase(pair, false);            // total bodies = (32-p) + (p+1) = 33, uniform
}

// ---------------------------------------------------------------------------
extern "C" void kernel_launch(void* const* d_in, const int* in_sizes, int n_in,
                              void* d_out, int out_size, void* d_ws, size_t ws_size,
                              hipStream_t stream)
{
  (void)in_sizes; (void)n_in; (void)out_size; (void)ws_size;
  const float* Q  = (const float*)d_in[0];
  const float* K  = (const float*)d_in[1];
  const float* V  = (const float*)d_in[2];
  const float* Wq = (const float*)d_in[4];
  const float* bq = (const float*)d_in[5];
  const float* Wk = (const float*)d_in[6];
  const float* bk = (const float*)d_in[7];
  const float* Wv = (const float*)d_in[8];
  const float* bv = (const float*)d_in[9];
  const float* Wo = (const float*)d_in[10];
  const float* bo = (const float*)d_in[11];
  float* out = (float*)d_out;

  const size_t NELT = (size_t)MROWS * D_MODEL;
  bf16_t* qp   = (bf16_t*)d_ws;                     // [B,H,S,DK] (pre-scaled)
  bf16_t* kp   = qp + NELT;                         // [B,H,S,DK]
  bf16_t* vtp  = kp + NELT;                         // [B,H,DK,S]
  bf16_t* obuf = vtp + NELT;                        // [B,S,H*DK]
  bf16_t* wqt  = obuf + NELT;                       // [3072][1024] contiguous:
  bf16_t* wkt  = wqt + (size_t)D_MODEL * D_MODEL;   //   wqt | wkt | wvt
  bf16_t* wvt  = wkt + (size_t)D_MODEL * D_MODEL;
  bf16_t* wot  = wvt + (size_t)D_MODEL * D_MODEL;

  dim3 blk(256);
  transpose_w_kernel<<<dim3(16, 16, 4), blk, 0, stream>>>(
      Wq, Wk, Wv, Wo, wqt, wkt, wvt, wot);

  qkv_kernel<<<dim3(3 * D_MODEL / 128, MROWS / 128), blk, 0, stream>>>(
      Q, K, V, wqt, bq, bk, bv, qp, kp, vtp);

  attn_kernel<<<dim3(16, BATCH * NHEAD), blk, 0, stream>>>(qp, kp, vtp, obuf);

  out_gemm_kernel<<<dim3(D_MODEL / 128, MROWS / 128), blk, 0, stream>>>(
      obuf, wot, bo, out);
}

// Round 3
// 366.895 us; speedup vs baseline: 1.0812x; 1.0812x over previous
//
#include <hip/hip_runtime.h>

typedef __bf16 bf16_t;
typedef __bf16 bf16x8 __attribute__((ext_vector_type(8)));
typedef __bf16 bf16x4 __attribute__((ext_vector_type(4)));
typedef float  floatx4 __attribute__((ext_vector_type(4)));

#define D_MODEL 1024
#define S_LEN   2048
#define NHEAD   16
#define DK      64
#define BATCH   4
#define MROWS   (BATCH * S_LEN)   // 8192
// 1/sqrt(64) * log2(e): fold into Q so scores arrive in exp2 domain
#define QSCALE  0.18033688011112042f

__device__ __forceinline__ void load_lds16(const void* gsrc, void* ldst) {
  __builtin_amdgcn_global_load_lds(
      (const __attribute__((address_space(1))) void*)gsrc,
      (__attribute__((address_space(3))) void*)ldst, 16, 0, 0);
}

__device__ __forceinline__ unsigned pack_bf16(float a, float b) {
  union { bf16_t h[2]; unsigned u; } t;
  t.h[0] = (bf16_t)a; t.h[1] = (bf16_t)b;
  return t.u;
}

__device__ __forceinline__ float bperm_f(int addr, float v) {
  union { float f; int i; } in, out;
  in.f = v;
  out.i = __builtin_amdgcn_ds_bpermute(addr, in.i);
  return out.f;
}

__device__ __forceinline__ void barrier_mem() {
  asm volatile("" ::: "memory");
  __builtin_amdgcn_s_barrier();
  asm volatile("" ::: "memory");
}

// ---------------------------------------------------------------------------
// fp32 -> bf16 convert of the three activation inputs into one [3][8192][1024]
// contiguous bf16 buffer (A operand of the 8-phase QKV GEMM).
// ---------------------------------------------------------------------------
__global__ __launch_bounds__(256)
void convert_a_kernel(const float* __restrict__ Q, const float* __restrict__ K,
                      const float* __restrict__ V, bf16_t* __restrict__ Abf)
{
  const int z = blockIdx.y;
  const float* src = z == 0 ? Q : (z == 1 ? K : V);
  bf16_t* dst = Abf + ((size_t)z << 23);          // z * 8192 * 1024
  const size_t off = ((size_t)blockIdx.x * 256 + threadIdx.x) * 8;
  floatx4 a = *(const floatx4*)&src[off];
  floatx4 b = *(const floatx4*)&src[off + 4];
  bf16x8 o;
  o[0] = (bf16_t)a[0]; o[1] = (bf16_t)a[1];
  o[2] = (bf16_t)a[2]; o[3] = (bf16_t)a[3];
  o[4] = (bf16_t)b[0]; o[5] = (bf16_t)b[1];
  o[6] = (bf16_t)b[2]; o[7] = (bf16_t)b[3];
  *(bf16x8*)&dst[off] = o;
}

// ---------------------------------------------------------------------------
// Fused weight transpose + fp32->bf16 for all 4 weights (z selects).
// wqt/wkt/wvt are contiguous -> form a [3072][1024] matrix for the QKV GEMM.
// ---------------------------------------------------------------------------
__global__ __launch_bounds__(256)
void transpose_w_kernel(const float* __restrict__ W0, const float* __restrict__ W1,
                        const float* __restrict__ W2, const float* __restrict__ W3,
                        bf16_t* __restrict__ T0, bf16_t* __restrict__ T1,
                        bf16_t* __restrict__ T2, bf16_t* __restrict__ T3)
{
  const int z = blockIdx.z;
  const float* W = z == 0 ? W0 : (z == 1 ? W1 : (z == 2 ? W2 : W3));
  bf16_t* Wt     = z == 0 ? T0 : (z == 1 ? T1 : (z == 2 ? T2 : T3));

  __shared__ float tile[64][65];
  const int x0 = blockIdx.x * 64;         // n
  const int y0 = blockIdx.y * 64;         // k
  const int tid = threadIdx.x;
  const int r = tid >> 4;
  const int c = (tid & 15) << 2;
#pragma unroll
  for (int p = 0; p < 4; p++) {
    floatx4 v = *(const floatx4*)&W[(size_t)(y0 + p * 16 + r) * D_MODEL + x0 + c];
    tile[p * 16 + r][c + 0] = v[0];
    tile[p * 16 + r][c + 1] = v[1];
    tile[p * 16 + r][c + 2] = v[2];
    tile[p * 16 + r][c + 3] = v[3];
  }
  __syncthreads();
#pragma unroll
  for (int p = 0; p < 4; p++) {
    int row = p * 16 + r;
    bf16x4 o;
    o[0] = (bf16_t)tile[c + 0][row];
    o[1] = (bf16_t)tile[c + 1][row];
    o[2] = (bf16_t)tile[c + 2][row];
    o[3] = (bf16_t)tile[c + 3][row];
    *(bf16x4*)&Wt[(size_t)(x0 + row) * D_MODEL + y0 + c] = o;
  }
}

// ---------------------------------------------------------------------------
// QKV projection as the 256x256 8-phase GEMM template (T2+T3+T4+T5):
//   M=8192, N=3072 (3 projections x 1024), K=1024. BM=BN=256, BK=64.
//   512 threads = 8 waves (2M x 4N); per-wave output 128x64 = acc[8][4].
//   LDS 128 KiB: [buf][A/B][half][128x64 bf16], XOR swizzle c^(row&7) applied
//   to BOTH the global_load_lds source chunk and the ds_read address
//   (involution), identical to the harness-verified attn staging.
//   Per phase: ds_read subtile || stage ONE half-tile (2 gll) || barrier ||
//   16 MFMA (setprio-wrapped) || barrier. vmcnt(2) ONLY at phases 4/8
//   (before the barrier), so 8-10 loads stay in flight across barriers.
//   Stage slots (iteration it; tiles u=2it buf0 @ph0-3, v=2it+1 buf1 @ph4-7):
//     ph0:A1(v) ph1:B0(v) ph2:B1(v) -> buf1 (read-complete since prev ph7)
//     ph3:A0(u+2) ph4:A1(u+2) ph5:B0(u+2) ph6:B1(u+2) -> buf0
//     ph7:A0(v+2) -> buf1.  Tail stages wrap (&15): harmless re-stage.
//   vmcnt(2)-per-wave + barrier = collective "all but my last stage landed".
// ---------------------------------------------------------------------------
__global__ __launch_bounds__(512, 2)
void qkv8_kernel(const bf16_t* __restrict__ Abf, const bf16_t* __restrict__ Wcat,
                 const float* __restrict__ bq, const float* __restrict__ bk,
                 const float* __restrict__ bv,
                 bf16_t* __restrict__ qo, bf16_t* __restrict__ ko,
                 bf16_t* __restrict__ vo)
{
  __shared__ bf16_t lds[2][2][2][128 * 64];   // 131072 B

  // Bijective XCD swizzle: 384 blocks, 8 XCDs x 48. XCD x gets bm in
  // [4x, 4x+4) over all 12 bn -> 4 A-panels (2 MB) resident per L2.
  const int orig = blockIdx.x;                 // 0..383
  const int L = (orig & 7) * 48 + (orig >> 3);
  const int bm = L / 12, bn = L % 12;
  const int m0 = bm << 8;
  const int n0 = bn << 8;
  const int z  = n0 >> 10;                     // projection (block-uniform)
  const bf16_t* A = Abf + ((size_t)z << 23);

  const int tid = threadIdx.x;
  const int wid = tid >> 6, lane = tid & 63;
  const int l15 = lane & 15, quad = lane >> 4;
  const int wm = wid >> 2, wn = wid & 3;

  floatx4 acc[8][4] = {};
  bf16x8 Af[4][2], Bf[2][2];

  auto stage_half = [&](int buf, int mat, int h, int kt) {
    const bf16_t* src = mat == 0 ? (A + (size_t)(m0 + (h << 7)) * D_MODEL)
                                 : (Wcat + (size_t)(n0 + (h << 7)) * D_MODEL);
    const int k0 = (kt & 15) << 6;
    bf16_t* dst = &lds[buf][mat][h][0];
#pragma unroll
    for (int p = 0; p < 2; p++) {
      const int slot = (p << 9) + tid;         // 0..1023
      const int row = slot >> 3;               // 0..127
      const int c = (slot & 7) ^ (row & 7);    // pre-swizzled source chunk
      load_lds16(&src[(size_t)row * D_MODEL + k0 + (c << 3)],
                 &dst[(size_t)((p << 9) + (wid << 6)) << 3]);
    }
  };

#define PHASE(BUF, MH, NH, LDA, LDB, SBUF, SMAT, SH, SKT, VMW)                 \
  {                                                                            \
    if (LDA) {                                                                 \
      _Pragma("unroll") for (int mi = 0; mi < 4; mi++) {                       \
        const int row = (((MH) * 4 + mi) << 4) + l15;                          \
        _Pragma("unroll") for (int ks = 0; ks < 2; ks++) {                     \
          const int ck = (ks << 2) + quad;                                     \
          Af[mi][ks] = *(const bf16x8*)&lds[BUF][0][wm]                        \
              [(row << 6) + ((ck ^ (row & 7)) << 3)];                          \
        }                                                                      \
      }                                                                        \
    }                                                                          \
    if (LDB) {                                                                 \
      _Pragma("unroll") for (int ni = 0; ni < 2; ni++) {                       \
        const int row = ((wn & 1) << 6) + (((NH) * 2 + ni) << 4) + l15;        \
        _Pragma("unroll") for (int ks = 0; ks < 2; ks++) {                     \
          const int ck = (ks << 2) + quad;                                     \
          Bf[ni][ks] = *(const bf16x8*)&lds[BUF][1][wn >> 1]                   \
              [(row << 6) + ((ck ^ (row & 7)) << 3)];                          \
        }                                                                      \
      }                                                                        \
    }                                                                          \
    stage_half(SBUF, SMAT, SH, SKT);                                           \
    barrier_mem();                                                             \
    __builtin_amdgcn_s_setprio(1);                                             \
    _Pragma("unroll") for (int mi = 0; mi < 4; mi++)                           \
      _Pragma("unroll") for (int ni = 0; ni < 2; ni++)                         \
        _Pragma("unroll") for (int ks = 0; ks < 2; ks++)                       \
          acc[(MH) * 4 + mi][(NH) * 2 + ni] =                                  \
              __builtin_amdgcn_mfma_f32_16x16x32_bf16(                         \
                  Af[mi][ks], Bf[ni][ks],                                      \
                  acc[(MH) * 4 + mi][(NH) * 2 + ni], 0, 0, 0);                 \
    __builtin_amdgcn_s_setprio(0);                                             \
    if (VMW) asm volatile("s_waitcnt vmcnt(2)" ::: "memory");                  \
    barrier_mem();                                                             \
  }

  // Prologue: tile0 (all 4 half-tiles) + A0(tile1); wait tile0 landed.
  stage_half(0, 0, 0, 0);
  stage_half(0, 0, 1, 0);
  stage_half(0, 1, 0, 0);
  stage_half(0, 1, 1, 0);
  stage_half(1, 0, 0, 1);
  asm volatile("s_waitcnt vmcnt(2)" ::: "memory");
  barrier_mem();

  for (int it = 0; it < 8; it++) {
    const int t1 = 2 * it + 1;
    const int t2 = 2 * it + 2;
    const int t3 = 2 * it + 3;
    PHASE(0, 0, 0, 1, 1, 1, 0, 1, t1, 0)   // quad(0,0): 8 A + 4 B reads
    PHASE(0, 0, 1, 0, 1, 1, 1, 0, t1, 0)   // quad(0,1): 4 B reads
    PHASE(0, 1, 1, 1, 0, 1, 1, 1, t1, 0)   // quad(1,1): 8 A reads
    PHASE(0, 1, 0, 0, 1, 0, 0, 0, t2, 1)   // quad(1,0): 4 B reads; vmcnt(2)
    PHASE(1, 0, 0, 1, 1, 0, 0, 1, t2, 0)
    PHASE(1, 0, 1, 0, 1, 0, 1, 0, t2, 0)
    PHASE(1, 1, 1, 1, 0, 0, 1, 1, t2, 0)
    PHASE(1, 1, 0, 0, 1, 1, 0, 0, t3, 1)   // vmcnt(2)
  }
  asm volatile("s_waitcnt vmcnt(0)" ::: "memory");  // drain tail stages

#undef PHASE

  const float* bias = z == 0 ? bq : (z == 1 ? bk : bv);
  bf16_t* outp      = z == 0 ? qo : (z == 1 ? ko : vo);
  const float scl   = (z == 0) ? QSCALE : 1.0f;
#pragma unroll
  for (int mi = 0; mi < 8; mi++) {
#pragma unroll
    for (int ni = 0; ni < 4; ni++) {
      const int nn = (n0 + (wn << 6) + (ni << 4) + l15) & (D_MODEL - 1);
      const float bvv = bias[nn];
      const int h = nn >> 6, d = nn & 63;
#pragma unroll
      for (int r = 0; r < 4; r++) {
        const int m = m0 + (wm << 7) + (mi << 4) + quad * 4 + r;
        const int b = m >> 11, srow = m & (S_LEN - 1);
        float v = (acc[mi][ni][r] + bvv) * scl;
        if (z < 2) {
          outp[((((size_t)(b * NHEAD + h) << 11) + srow) << 6) + d] = (bf16_t)v;
        } else {
          outp[((((size_t)(b * NHEAD + h) << 6) + d) << 11) + srow] = (bf16_t)v;
        }
      }
    }
  }
}

// ---------------------------------------------------------------------------
// LEGACY QKV (round-0 verified, 24 KB LDS, serial staging) — fallback when
// ws_size cannot hold the bf16 A buffer. Reads fp32 A directly.
// ---------------------------------------------------------------------------
__global__ __launch_bounds__(256, 3)
void qkv_legacy_kernel(const float* __restrict__ Qi, const float* __restrict__ Ki,
                       const float* __restrict__ Vi, const bf16_t* __restrict__ Wcat,
                       const float* __restrict__ bq, const float* __restrict__ bk,
                       const float* __restrict__ bv,
                       bf16_t* __restrict__ qo, bf16_t* __restrict__ ko,
                       bf16_t* __restrict__ vo)
{
  __shared__ float  Asf[128 * 32];
  __shared__ bf16_t Bs[128 * 32];

  const int L = blockIdx.x + 24 * blockIdx.y;
  const int j = (L >> 3) & 7;
  const int s = ((L >> 6) << 3) | (L & 7);
  const int z = s >> 6;
  const int n0g = (((z << 3) | j)) << 7;
  const int m0 = (s & 63) << 7;

  const float* A = z == 0 ? Qi : (z == 1 ? Ki : Vi);

  const int tid = threadIdx.x;
  const int lane = tid & 63;
  const int w = tid >> 6;
  const int l15 = lane & 15;
  const int quad = lane >> 4;
  const int wy = (w >> 1) << 6;
  const int wx = (w & 1) << 6;
  const int w64 = w << 6;

  floatx4 acc[4][4];
#pragma unroll
  for (int i = 0; i < 4; i++)
#pragma unroll
    for (int jj = 0; jj < 4; jj++)
#pragma unroll
      for (int r = 0; r < 4; r++) acc[i][jj][r] = 0.0f;

  for (int kt = 0; kt < 32; kt++) {
    const int k0 = kt << 5;
    __syncthreads();
#pragma unroll
    for (int p = 0; p < 2; p++) {
      int slot = p * 256 + w64 + lane;
      int row = slot >> 2;
      int kc = (slot & 3) ^ (row & 3);
      load_lds16(&Wcat[(size_t)(n0g + row) * D_MODEL + k0 + (kc << 3)],
                 &Bs[(size_t)(p * 256 + w64) << 3]);
    }
#pragma unroll
    for (int p = 0; p < 4; p++) {
      int sbase = (w << 8) + (p << 6);
      int slot = sbase + lane;
      int row = slot >> 3;
      int ca = (slot & 7) ^ (row & 7);
      load_lds16(&A[(size_t)(m0 + row) * D_MODEL + k0 + (ca << 2)],
                 &Asf[(size_t)sbase << 2]);
    }
    __syncthreads();

    bf16x8 af[4], bfv[4];
#pragma unroll
    for (int mi = 0; mi < 4; mi++) {
      const int m = wy + mi * 16 + l15;
      const int e = m & 7;
      floatx4 f0 = *(const floatx4*)&Asf[(m << 5) + ((((quad << 1))     ^ e) << 2)];
      floatx4 f1 = *(const floatx4*)&Asf[(m << 5) + ((((quad << 1) | 1) ^ e) << 2)];
      bf16x8 o;
      o[0] = (bf16_t)f0[0]; o[1] = (bf16_t)f0[1];
      o[2] = (bf16_t)f0[2]; o[3] = (bf16_t)f0[3];
      o[4] = (bf16_t)f1[0]; o[5] = (bf16_t)f1[1];
      o[6] = (bf16_t)f1[2]; o[7] = (bf16_t)f1[3];
      af[mi] = o;
    }
#pragma unroll
    for (int ni = 0; ni < 4; ni++) {
      int n = wx + ni * 16 + l15;
      bfv[ni] = *(const bf16x8*)&Bs[n * 32 + ((quad ^ (n & 3)) << 3)];
    }
#pragma unroll
    for (int mi = 0; mi < 4; mi++)
#pragma unroll
      for (int ni = 0; ni < 4; ni++)
        acc[mi][ni] = __builtin_amdgcn_mfma_f32_16x16x32_bf16(
            af[mi], bfv[ni], acc[mi][ni], 0, 0, 0);
  }

  const float* bias = z == 0 ? bq : (z == 1 ? bk : bv);
  bf16_t* outp      = z == 0 ? qo : (z == 1 ? ko : vo);
  const float scl   = (z == 0) ? QSCALE : 1.0f;
#pragma unroll
  for (int mi = 0; mi < 4; mi++) {
#pragma unroll
    for (int ni = 0; ni < 4; ni++) {
      const int nn = (n0g + wx + ni * 16 + l15) & (D_MODEL - 1);
      const float bvv = bias[nn];
      const int h = nn >> 6, d = nn & 63;
#pragma unroll
      for (int r = 0; r < 4; r++) {
        const int m = m0 + wy + mi * 16 + quad * 4 + r;
        const int b = m >> 11, srow = m & (S_LEN - 1);
        float v = (acc[mi][ni][r] + bvv) * scl;
        if (z < 2) {
          outp[((((size_t)(b * NHEAD + h) << 11) + srow) << 6) + d] = (bf16_t)v;
        } else {
          outp[((((size_t)(b * NHEAD + h) << 6) + d) << 11) + srow] = (bf16_t)v;
        }
      }
    }
  }
}

// ---------------------------------------------------------------------------
// Output GEMM: out = obuf(bf16) @ Wo + bo, fp32 out. Dual global_load_lds.
// (round-0 proven serial form)
// ---------------------------------------------------------------------------
__global__ __launch_bounds__(256)
void out_gemm_kernel(const bf16_t* __restrict__ A, const bf16_t* __restrict__ Wt,
                     const float* __restrict__ bias, float* __restrict__ out)
{
  __shared__ bf16_t As[128 * 32];
  __shared__ bf16_t Bs[128 * 32];
  const int L = blockIdx.x + 8 * blockIdx.y;      // 0..511
  const int n0 = (((L >> 3) & 7)) << 7;
  const int m0 = ((((L >> 6) << 3) | (L & 7))) << 7;
  const int tid = threadIdx.x;
  const int lane = tid & 63;
  const int w = tid >> 6;
  const int l15 = lane & 15;
  const int quad = lane >> 4;
  const int wy = (w >> 1) << 6;
  const int wx = (w & 1) << 6;
  const int w64 = w << 6;

  floatx4 acc[4][4];
#pragma unroll
  for (int i = 0; i < 4; i++)
#pragma unroll
    for (int jj = 0; jj < 4; jj++)
#pragma unroll
      for (int r = 0; r < 4; r++) acc[i][jj][r] = 0.0f;

  for (int kt = 0; kt < 32; kt++) {
    const int k0 = kt << 5;
    __syncthreads();
#pragma unroll
    for (int p = 0; p < 2; p++) {
      int slot = p * 256 + w64 + lane;
      int row = slot >> 2;
      int kc = (slot & 3) ^ (row & 3);
      load_lds16(&A[(size_t)(m0 + row) * D_MODEL + k0 + (kc << 3)],
                 &As[(size_t)(p * 256 + w64) << 3]);
      load_lds16(&Wt[(size_t)(n0 + row) * D_MODEL + k0 + (kc << 3)],
                 &Bs[(size_t)(p * 256 + w64) << 3]);
    }
    __syncthreads();

    bf16x8 af[4], bfv[4];
#pragma unroll
    for (int mi = 0; mi < 4; mi++) {
      int m = wy + mi * 16 + l15;
      af[mi] = *(const bf16x8*)&As[m * 32 + ((quad ^ (m & 3)) << 3)];
    }
#pragma unroll
    for (int ni = 0; ni < 4; ni++) {
      int n = wx + ni * 16 + l15;
      bfv[ni] = *(const bf16x8*)&Bs[n * 32 + ((quad ^ (n & 3)) << 3)];
    }
#pragma unroll
    for (int mi = 0; mi < 4; mi++)
#pragma unroll
      for (int ni = 0; ni < 4; ni++)
        acc[mi][ni] = __builtin_amdgcn_mfma_f32_16x16x32_bf16(
            af[mi], bfv[ni], acc[mi][ni], 0, 0, 0);
  }

#pragma unroll
  for (int mi = 0; mi < 4; mi++) {
#pragma unroll
    for (int ni = 0; ni < 4; ni++) {
      const int nbase = n0 + wx + ni * 16 + l15;
      const float bv = bias[nbase];
#pragma unroll
      for (int r = 0; r < 4; r++) {
        const int m = m0 + wy + mi * 16 + quad * 4 + r;
        out[((size_t)m << 10) + nbase] = acc[mi][ni][r] + bv;
      }
    }
  }
}

// ---------------------------------------------------------------------------
// Causal flash attention, S^T formulation, BALANCED pairing (r5-verified).
// ---------------------------------------------------------------------------
__global__ __launch_bounds__(256, 4)
void attn_kernel(const bf16_t* __restrict__ qp, const bf16_t* __restrict__ kp,
                 const bf16_t* __restrict__ vtp, bf16_t* __restrict__ ob)
{
  __shared__ bf16_t Kt0[64 * 64];
  __shared__ bf16_t Kt1[64 * 64];
  __shared__ bf16_t Vt0[64 * 64];
  __shared__ bf16_t Vt1[64 * 64];

  const int pair = blockIdx.x;             // 0..15
  const int bh = blockIdx.y;               // 0..63
  const int tid = threadIdx.x;
  const int w = tid >> 6;
  const int lane = tid & 63;
  const int l15 = lane & 15;
  const int quad = lane >> 4;

  const bf16_t* Qh = qp + ((size_t)bh << 17);
  const bf16_t* Kh = kp + ((size_t)bh << 17);
  const bf16_t* Vh = vtp + ((size_t)bh << 17);   // [64][2048]
  const int b = bh >> 4, h = bh & 15;

  auto stage = [&](int k0s, bf16_t* dK, bf16_t* dV) {
#pragma unroll
    for (int p = 0; p < 2; p++) {
      const int sbase = (w << 7) + (p << 6);
      const int slot = sbase + lane;
      const int row = slot >> 3;
      const int c = (slot & 7) ^ (row & 7);
      load_lds16(&Kh[((size_t)(k0s + row) << 6) + (c << 3)], &dK[sbase << 3]);
      load_lds16(&Vh[((size_t)row << 11) + k0s + (c << 3)], &dV[sbase << 3]);
    }
  };

  int par = 0;   // global tile-counter parity: current buffer index

  auto phase = [&](int qt, bool prefetch_next_phase) {
    const int q0 = qt << 6;
    const int qbase = q0 + (w << 4);       // wave's 16 q-rows
    const int nkb = qt + 1;

    bf16x8 qf[2];
#pragma unroll
    for (int ks = 0; ks < 2; ks++)
      qf[ks] = *(const bf16x8*)&Qh[(size_t)(qbase + l15) * DK +
                                   ks * 32 + (quad << 3)];

    floatx4 acc_o[4];
    float m_i = -1e30f, l_i = 0.0f;
#pragma unroll
    for (int nd = 0; nd < 4; nd++)
#pragma unroll
      for (int r = 0; r < 4; r++) acc_o[nd][r] = 0.0f;

    for (int kb = 0; kb < nkb; kb++) {
      const int k0 = kb << 6;
      __syncthreads();   // drains this tile's gll (issued one body ago)

      const bf16_t* cK = par ? Kt1 : Kt0;
      const bf16_t* cV = par ? Vt1 : Vt0;
      bf16_t* nK = par ? Kt0 : Kt1;
      bf16_t* nV = par ? Vt0 : Vt1;

      if (kb + 1 < nkb)             stage((kb + 1) << 6, nK, nV);
      else if (prefetch_next_phase) stage(0, nK, nV);

      bf16x8 bk[2][4];
#pragma unroll
      for (int ks = 0; ks < 2; ks++)
#pragma unroll
        for (int ni = 0; ni < 4; ni++) {
          const int row = ni * 16 + l15;
          const int cp = ((ks << 2) + quad) ^ (row & 7);
          bk[ks][ni] = *(const bf16x8*)&cK[(row << 6) + (cp << 3)];
        }

      floatx4 st[4];
#pragma unroll
      for (int ni = 0; ni < 4; ni++)
#pragma unroll
        for (int r = 0; r < 4; r++) st[ni][r] = 0.0f;
#pragma unroll
      for (int ks = 0; ks < 2; ks++)
#pragma unroll
        for (int ni = 0; ni < 4; ni++)
          st[ni] = __builtin_amdgcn_mfma_f32_16x16x32_bf16(
              bk[ks][ni], qf[ks], st[ni], 0, 0, 0);

      if (k0 + 63 > qbase) {
        const int qrow = qbase + l15;
#pragma unroll
        for (int ni = 0; ni < 4; ni++) {
          const int keyb = k0 + ni * 16 + quad * 4;
#pragma unroll
          for (int r = 0; r < 4; r++)
            if (keyb + r > qrow) st[ni][r] = -1e30f;
        }
      }

      float v = st[0][0];
#pragma unroll
      for (int ni = 0; ni < 4; ni++)
#pragma unroll
        for (int r = 0; r < 4; r++) v = fmaxf(v, st[ni][r]);
      v = fmaxf(v, __shfl_xor(v, 16));
      v = fmaxf(v, __shfl_xor(v, 32));
      const float mn = fmaxf(m_i, v);
      const float alpha = __builtin_amdgcn_exp2f(m_i - mn);
      m_i = mn;

      unsigned pd[4][2];
      float ssum = 0.0f;
#pragma unroll
      for (int c = 0; c < 4; c++)
#pragma unroll
        for (int hh = 0; hh < 2; hh++) {
          float p0 = __builtin_amdgcn_exp2f(st[c][2 * hh]     - m_i);
          float p1 = __builtin_amdgcn_exp2f(st[c][2 * hh + 1] - m_i);
          ssum += p0 + p1;
          pd[c][hh] = pack_bf16(p0, p1);
        }
      ssum += __shfl_xor(ssum, 16);
      ssum += __shfl_xor(ssum, 32);
      l_i = l_i * alpha + ssum;

#pragma unroll
      for (int r = 0; r < 4; r++) {
        float ab = bperm_f((quad * 4 + r) << 2, alpha);
#pragma unroll
        for (int nd = 0; nd < 4; nd++) acc_o[nd][r] *= ab;
      }

      union AV { unsigned u[4]; bf16x8 v; };
      AV av[2];
#pragma unroll
      for (int ks = 0; ks < 2; ks++)
#pragma unroll
        for (int i = 0; i < 4; i++) {
          const int addr = ((((2 * quad + (i >> 1)) & 3) << 4) | l15) << 2;
          int lo = __builtin_amdgcn_ds_bpermute(addr, (int)pd[ks * 2][i & 1]);
          int hi = __builtin_amdgcn_ds_bpermute(addr, (int)pd[ks * 2 + 1][i & 1]);
          av[ks].u[i] = (unsigned)(quad >= 2 ? hi : lo);
        }

#pragma unroll
      for (int ks = 0; ks < 2; ks++) {
        bf16x8 bvv[4];
#pragma unroll
        for (int nd = 0; nd < 4; nd++) {
          const int row = nd * 16 + l15;
          const int cp = ((ks << 2) + quad) ^ (row & 7);
          bvv[nd] = *(const bf16x8*)&cV[(row << 6) + (cp << 3)];
        }
#pragma unroll
        for (int nd = 0; nd < 4; nd++)
          acc_o[nd] = __builtin_amdgcn_mfma_f32_16x16x32_bf16(
              av[ks].v, bvv[nd], acc_o[nd], 0, 0, 0);
      }

      par ^= 1;
    }

    const float inv = 1.0f / l_i;
#pragma unroll
    for (int r = 0; r < 4; r++) {
      const float linv = bperm_f((quad * 4 + r) << 2, inv);
      const int sRow = qbase + quad * 4 + r;
#pragma unroll
      for (int nd = 0; nd < 4; nd++) {
        const int d = nd * 16 + l15;
        ob[(((size_t)(b * S_LEN + sRow)) << 10) + h * 64 + d] =
            (bf16_t)(acc_o[nd][r] * linv);
      }
    }
  };

  stage(0, Kt0, Vt0);            // tile 0 of phase A into buffer 0
  phase(31 - pair, true);        // big tile first; prefetch B's tile 0 at seam
  phase(pair, false);            // total bodies = (32-p) + (p+1) = 33, uniform
}

// ---------------------------------------------------------------------------
extern "C" void kernel_launch(void* const* d_in, const int* in_sizes, int n_in,
                              void* d_out, int out_size, void* d_ws, size_t ws_size,
                              hipStream_t stream)
{
  (void)in_sizes; (void)n_in; (void)out_size;
  const float* Q  = (const float*)d_in[0];
  const float* K  = (const float*)d_in[1];
  const float* V  = (const float*)d_in[2];
  const float* Wq = (const float*)d_in[4];
  const float* bq = (const float*)d_in[5];
  const float* Wk = (const float*)d_in[6];
  const float* bk = (const float*)d_in[7];
  const float* Wv = (const float*)d_in[8];
  const float* bv = (const float*)d_in[9];
  const float* Wo = (const float*)d_in[10];
  const float* bo = (const float*)d_in[11];
  float* out = (float*)d_out;

  const size_t NELT = (size_t)MROWS * D_MODEL;        // 8 Mi elements
  const size_t WELT = (size_t)D_MODEL * D_MODEL;      // 1 Mi elements

  // New layout (104 MB): qp|kp|vtp (48MB) | weights (8MB) | abf (48MB).
  // obuf ALIASES abf (abf dead after qkv8; obuf born after).
  const size_t need_new = (3 * NELT + 4 * WELT + 3 * NELT) * sizeof(bf16_t);

  bf16_t* qp   = (bf16_t*)d_ws;
  bf16_t* kp   = qp + NELT;
  bf16_t* vtp  = kp + NELT;
  bf16_t* wqt  = vtp + NELT;
  bf16_t* wkt  = wqt + WELT;
  bf16_t* wvt  = wkt + WELT;
  bf16_t* wot  = wvt + WELT;
  bf16_t* abf  = wot + WELT;       // [3][8192][1024] bf16 (new path only)
  bf16_t* obuf = abf;              // alias: lives in abf's first 16MB

  dim3 blk(256);
  transpose_w_kernel<<<dim3(16, 16, 4), blk, 0, stream>>>(
      Wq, Wk, Wv, Wo, wqt, wkt, wvt, wot);

  if (ws_size >= need_new) {
    convert_a_kernel<<<dim3(MROWS * D_MODEL / (256 * 8), 3), blk, 0, stream>>>(
        Q, K, V, abf);
    qkv8_kernel<<<dim3((MROWS / 256) * (3 * D_MODEL / 256)), dim3(512), 0,
                  stream>>>(abf, wqt, bq, bk, bv, qp, kp, vtp);
  } else {
    // Fallback (72 MB, round-0 verified): obuf sits where abf would start.
    qkv_legacy_kernel<<<dim3(3 * D_MODEL / 128, MROWS / 128), blk, 0, stream>>>(
        Q, K, V, wqt, bq, bk, bv, qp, kp, vtp);
  }

  attn_kernel<<<dim3(16, BATCH * NHEAD), blk, 0, stream>>>(qp, kp, vtp, obuf);

  out_gemm_kernel<<<dim3(D_MODEL / 128, MROWS / 128), blk, 0, stream>>>(
      obuf, wot, bo, out);
}

// Round 4
// 362.510 us; speedup vs baseline: 1.0943x; 1.0121x over previous
//
#include <hip/hip_runtime.h>

typedef __bf16 bf16_t;
typedef __bf16 bf16x8 __attribute__((ext_vector_type(8)));
typedef __bf16 bf16x4 __attribute__((ext_vector_type(4)));
typedef float  floatx4 __attribute__((ext_vector_type(4)));

#define D_MODEL 1024
#define S_LEN   2048
#define NHEAD   16
#define DK      64
#define BATCH   4
#define MROWS   (BATCH * S_LEN)   // 8192
// 1/sqrt(64) * log2(e): fold into Q so scores arrive in exp2 domain
#define QSCALE  0.18033688011112042f

__device__ __forceinline__ void load_lds16(const void* gsrc, void* ldst) {
  __builtin_amdgcn_global_load_lds(
      (const __attribute__((address_space(1))) void*)gsrc,
      (__attribute__((address_space(3))) void*)ldst, 16, 0, 0);
}

__device__ __forceinline__ unsigned pack_bf16(float a, float b) {
  union { bf16_t h[2]; unsigned u; } t;
  t.h[0] = (bf16_t)a; t.h[1] = (bf16_t)b;
  return t.u;
}

__device__ __forceinline__ float bperm_f(int addr, float v) {
  union { float f; int i; } in, out;
  in.f = v;
  out.i = __builtin_amdgcn_ds_bpermute(addr, in.i);
  return out.f;
}

__device__ __forceinline__ void barrier_mem() {
  asm volatile("" ::: "memory");
  __builtin_amdgcn_s_barrier();
  asm volatile("" ::: "memory");
}

// ---------------------------------------------------------------------------
// fp32 -> bf16 convert of the three activation inputs into one [3][8192][1024]
// contiguous bf16 buffer (A operand of the 8-phase QKV GEMM).
// ---------------------------------------------------------------------------
__global__ __launch_bounds__(256)
void convert_a_kernel(const float* __restrict__ Q, const float* __restrict__ K,
                      const float* __restrict__ V, bf16_t* __restrict__ Abf)
{
  const int z = blockIdx.y;
  const float* src = z == 0 ? Q : (z == 1 ? K : V);
  bf16_t* dst = Abf + ((size_t)z << 23);          // z * 8192 * 1024
  const size_t off = ((size_t)blockIdx.x * 256 + threadIdx.x) * 8;
  floatx4 a = *(const floatx4*)&src[off];
  floatx4 b = *(const floatx4*)&src[off + 4];
  bf16x8 o;
  o[0] = (bf16_t)a[0]; o[1] = (bf16_t)a[1];
  o[2] = (bf16_t)a[2]; o[3] = (bf16_t)a[3];
  o[4] = (bf16_t)b[0]; o[5] = (bf16_t)b[1];
  o[6] = (bf16_t)b[2]; o[7] = (bf16_t)b[3];
  *(bf16x8*)&dst[off] = o;
}

// ---------------------------------------------------------------------------
// Fused weight transpose + fp32->bf16 for all 4 weights (z selects).
// wqt/wkt/wvt are contiguous -> form a [3072][1024] matrix for the QKV GEMM.
// ---------------------------------------------------------------------------
__global__ __launch_bounds__(256)
void transpose_w_kernel(const float* __restrict__ W0, const float* __restrict__ W1,
                        const float* __restrict__ W2, const float* __restrict__ W3,
                        bf16_t* __restrict__ T0, bf16_t* __restrict__ T1,
                        bf16_t* __restrict__ T2, bf16_t* __restrict__ T3)
{
  const int z = blockIdx.z;
  const float* W = z == 0 ? W0 : (z == 1 ? W1 : (z == 2 ? W2 : W3));
  bf16_t* Wt     = z == 0 ? T0 : (z == 1 ? T1 : (z == 2 ? T2 : T3));

  __shared__ float tile[64][65];
  const int x0 = blockIdx.x * 64;         // n
  const int y0 = blockIdx.y * 64;         // k
  const int tid = threadIdx.x;
  const int r = tid >> 4;
  const int c = (tid & 15) << 2;
#pragma unroll
  for (int p = 0; p < 4; p++) {
    floatx4 v = *(const floatx4*)&W[(size_t)(y0 + p * 16 + r) * D_MODEL + x0 + c];
    tile[p * 16 + r][c + 0] = v[0];
    tile[p * 16 + r][c + 1] = v[1];
    tile[p * 16 + r][c + 2] = v[2];
    tile[p * 16 + r][c + 3] = v[3];
  }
  __syncthreads();
#pragma unroll
  for (int p = 0; p < 4; p++) {
    int row = p * 16 + r;
    bf16x4 o;
    o[0] = (bf16_t)tile[c + 0][row];
    o[1] = (bf16_t)tile[c + 1][row];
    o[2] = (bf16_t)tile[c + 2][row];
    o[3] = (bf16_t)tile[c + 3][row];
    *(bf16x4*)&Wt[(size_t)(x0 + row) * D_MODEL + y0 + c] = o;
  }
}

// ---------------------------------------------------------------------------
// QKV projection as the 256x256 8-phase GEMM template (T2+T3+T4+T5):
//   M=8192, N=3072 (3 projections x 1024), K=1024. BM=BN=256, BK=64.
//   512 threads = 8 waves (2M x 4N); per-wave output 128x64 = acc[8][4].
//   LDS 128 KiB: [buf][A/B][half][128x64 bf16], XOR swizzle c^(row&7) applied
//   to BOTH the global_load_lds source chunk and the ds_read address
//   (involution), identical to the harness-verified attn staging.
//   Per phase: ds_read subtile || stage ONE half-tile (2 gll) || barrier ||
//   16 MFMA (setprio-wrapped) || barrier. vmcnt(2) ONLY at phases 4/8
//   (before the barrier), so 8-10 loads stay in flight across barriers.
//   Stage slots (iteration it; tiles u=2it buf0 @ph0-3, v=2it+1 buf1 @ph4-7):
//     ph0:A1(v) ph1:B0(v) ph2:B1(v) -> buf1 (read-complete since prev ph7)
//     ph3:A0(u+2) ph4:A1(u+2) ph5:B0(u+2) ph6:B1(u+2) -> buf0
//     ph7:A0(v+2) -> buf1.  Tail stages wrap (&15): harmless re-stage.
//   vmcnt(2)-per-wave + barrier = collective "all but my last stage landed".
// ---------------------------------------------------------------------------
__global__ __launch_bounds__(512, 2)
void qkv8_kernel(const bf16_t* __restrict__ Abf, const bf16_t* __restrict__ Wcat,
                 const float* __restrict__ bq, const float* __restrict__ bk,
                 const float* __restrict__ bv,
                 bf16_t* __restrict__ qo, bf16_t* __restrict__ ko,
                 bf16_t* __restrict__ vo)
{
  __shared__ bf16_t lds[2][2][2][128 * 64];   // 131072 B

  // Bijective XCD swizzle: 384 blocks, 8 XCDs x 48. XCD x gets bm in
  // [4x, 4x+4) over all 12 bn -> 4 A-panels (2 MB) resident per L2.
  const int orig = blockIdx.x;                 // 0..383
  const int L = (orig & 7) * 48 + (orig >> 3);
  const int bm = L / 12, bn = L % 12;
  const int m0 = bm << 8;
  const int n0 = bn << 8;
  const int z  = n0 >> 10;                     // projection (block-uniform)
  const bf16_t* A = Abf + ((size_t)z << 23);

  const int tid = threadIdx.x;
  const int wid = tid >> 6, lane = tid & 63;
  const int l15 = lane & 15, quad = lane >> 4;
  const int wm = wid >> 2, wn = wid & 3;

  floatx4 acc[8][4] = {};
  bf16x8 Af[4][2], Bf[2][2];

  auto stage_half = [&](int buf, int mat, int h, int kt) {
    const bf16_t* src = mat == 0 ? (A + (size_t)(m0 + (h << 7)) * D_MODEL)
                                 : (Wcat + (size_t)(n0 + (h << 7)) * D_MODEL);
    const int k0 = (kt & 15) << 6;
    bf16_t* dst = &lds[buf][mat][h][0];
#pragma unroll
    for (int p = 0; p < 2; p++) {
      const int slot = (p << 9) + tid;         // 0..1023
      const int row = slot >> 3;               // 0..127
      const int c = (slot & 7) ^ (row & 7);    // pre-swizzled source chunk
      load_lds16(&src[(size_t)row * D_MODEL + k0 + (c << 3)],
                 &dst[(size_t)((p << 9) + (wid << 6)) << 3]);
    }
  };

#define PHASE(BUF, MH, NH, LDA, LDB, SBUF, SMAT, SH, SKT, VMW)                 \
  {                                                                            \
    if (LDA) {                                                                 \
      _Pragma("unroll") for (int mi = 0; mi < 4; mi++) {                       \
        const int row = (((MH) * 4 + mi) << 4) + l15;                          \
        _Pragma("unroll") for (int ks = 0; ks < 2; ks++) {                     \
          const int ck = (ks << 2) + quad;                                     \
          Af[mi][ks] = *(const bf16x8*)&lds[BUF][0][wm]                        \
              [(row << 6) + ((ck ^ (row & 7)) << 3)];                          \
        }                                                                      \
      }                                                                        \
    }                                                                          \
    if (LDB) {                                                                 \
      _Pragma("unroll") for (int ni = 0; ni < 2; ni++) {                       \
        const int row = ((wn & 1) << 6) + (((NH) * 2 + ni) << 4) + l15;        \
        _Pragma("unroll") for (int ks = 0; ks < 2; ks++) {                     \
          const int ck = (ks << 2) + quad;                                     \
          Bf[ni][ks] = *(const bf16x8*)&lds[BUF][1][wn >> 1]                   \
              [(row << 6) + ((ck ^ (row & 7)) << 3)];                          \
        }                                                                      \
      }                                                                        \
    }                                                                          \
    stage_half(SBUF, SMAT, SH, SKT);                                           \
    barrier_mem();                                                             \
    __builtin_amdgcn_s_setprio(1);                                             \
    _Pragma("unroll") for (int mi = 0; mi < 4; mi++)                           \
      _Pragma("unroll") for (int ni = 0; ni < 2; ni++)                         \
        _Pragma("unroll") for (int ks = 0; ks < 2; ks++)                       \
          acc[(MH) * 4 + mi][(NH) * 2 + ni] =                                  \
              __builtin_amdgcn_mfma_f32_16x16x32_bf16(                         \
                  Af[mi][ks], Bf[ni][ks],                                      \
                  acc[(MH) * 4 + mi][(NH) * 2 + ni], 0, 0, 0);                 \
    __builtin_amdgcn_s_setprio(0);                                             \
    if (VMW) asm volatile("s_waitcnt vmcnt(2)" ::: "memory");                  \
    barrier_mem();                                                             \
  }

  // Prologue: tile0 (all 4 half-tiles) + A0(tile1); wait tile0 landed.
  stage_half(0, 0, 0, 0);
  stage_half(0, 0, 1, 0);
  stage_half(0, 1, 0, 0);
  stage_half(0, 1, 1, 0);
  stage_half(1, 0, 0, 1);
  asm volatile("s_waitcnt vmcnt(2)" ::: "memory");
  barrier_mem();

  for (int it = 0; it < 8; it++) {
    const int t1 = 2 * it + 1;
    const int t2 = 2 * it + 2;
    const int t3 = 2 * it + 3;
    PHASE(0, 0, 0, 1, 1, 1, 0, 1, t1, 0)   // quad(0,0): 8 A + 4 B reads
    PHASE(0, 0, 1, 0, 1, 1, 1, 0, t1, 0)   // quad(0,1): 4 B reads
    PHASE(0, 1, 1, 1, 0, 1, 1, 1, t1, 0)   // quad(1,1): 8 A reads
    PHASE(0, 1, 0, 0, 1, 0, 0, 0, t2, 1)   // quad(1,0): 4 B reads; vmcnt(2)
    PHASE(1, 0, 0, 1, 1, 0, 0, 1, t2, 0)
    PHASE(1, 0, 1, 0, 1, 0, 1, 0, t2, 0)
    PHASE(1, 1, 1, 1, 0, 0, 1, 1, t2, 0)
    PHASE(1, 1, 0, 0, 1, 1, 0, 0, t3, 1)   // vmcnt(2)
  }
  asm volatile("s_waitcnt vmcnt(0)" ::: "memory");  // drain tail stages

#undef PHASE

  const float* bias = z == 0 ? bq : (z == 1 ? bk : bv);
  bf16_t* outp      = z == 0 ? qo : (z == 1 ? ko : vo);
  const float scl   = (z == 0) ? QSCALE : 1.0f;
#pragma unroll
  for (int mi = 0; mi < 8; mi++) {
#pragma unroll
    for (int ni = 0; ni < 4; ni++) {
      const int nn = (n0 + (wn << 6) + (ni << 4) + l15) & (D_MODEL - 1);
      const float bvv = bias[nn];
      const int h = nn >> 6, d = nn & 63;
#pragma unroll
      for (int r = 0; r < 4; r++) {
        const int m = m0 + (wm << 7) + (mi << 4) + quad * 4 + r;
        const int b = m >> 11, srow = m & (S_LEN - 1);
        float v = (acc[mi][ni][r] + bvv) * scl;
        if (z < 2) {
          outp[((((size_t)(b * NHEAD + h) << 11) + srow) << 6) + d] = (bf16_t)v;
        } else {
          outp[((((size_t)(b * NHEAD + h) << 6) + d) << 11) + srow] = (bf16_t)v;
        }
      }
    }
  }
}

// ---------------------------------------------------------------------------
// LEGACY QKV (round-0 verified, 24 KB LDS, serial staging) — fallback when
// ws_size cannot hold the bf16 A buffer. Reads fp32 A directly.
// ---------------------------------------------------------------------------
__global__ __launch_bounds__(256, 3)
void qkv_legacy_kernel(const float* __restrict__ Qi, const float* __restrict__ Ki,
                       const float* __restrict__ Vi, const bf16_t* __restrict__ Wcat,
                       const float* __restrict__ bq, const float* __restrict__ bk,
                       const float* __restrict__ bv,
                       bf16_t* __restrict__ qo, bf16_t* __restrict__ ko,
                       bf16_t* __restrict__ vo)
{
  __shared__ float  Asf[128 * 32];
  __shared__ bf16_t Bs[128 * 32];

  const int L = blockIdx.x + 24 * blockIdx.y;
  const int j = (L >> 3) & 7;
  const int s = ((L >> 6) << 3) | (L & 7);
  const int z = s >> 6;
  const int n0g = (((z << 3) | j)) << 7;
  const int m0 = (s & 63) << 7;

  const float* A = z == 0 ? Qi : (z == 1 ? Ki : Vi);

  const int tid = threadIdx.x;
  const int lane = tid & 63;
  const int w = tid >> 6;
  const int l15 = lane & 15;
  const int quad = lane >> 4;
  const int wy = (w >> 1) << 6;
  const int wx = (w & 1) << 6;
  const int w64 = w << 6;

  floatx4 acc[4][4];
#pragma unroll
  for (int i = 0; i < 4; i++)
#pragma unroll
    for (int jj = 0; jj < 4; jj++)
#pragma unroll
      for (int r = 0; r < 4; r++) acc[i][jj][r] = 0.0f;

  for (int kt = 0; kt < 32; kt++) {
    const int k0 = kt << 5;
    __syncthreads();
#pragma unroll
    for (int p = 0; p < 2; p++) {
      int slot = p * 256 + w64 + lane;
      int row = slot >> 2;
      int kc = (slot & 3) ^ (row & 3);
      load_lds16(&Wcat[(size_t)(n0g + row) * D_MODEL + k0 + (kc << 3)],
                 &Bs[(size_t)(p * 256 + w64) << 3]);
    }
#pragma unroll
    for (int p = 0; p < 4; p++) {
      int sbase = (w << 8) + (p << 6);
      int slot = sbase + lane;
      int row = slot >> 3;
      int ca = (slot & 7) ^ (row & 7);
      load_lds16(&A[(size_t)(m0 + row) * D_MODEL + k0 + (ca << 2)],
                 &Asf[(size_t)sbase << 2]);
    }
    __syncthreads();

    bf16x8 af[4], bfv[4];
#pragma unroll
    for (int mi = 0; mi < 4; mi++) {
      const int m = wy + mi * 16 + l15;
      const int e = m & 7;
      floatx4 f0 = *(const floatx4*)&Asf[(m << 5) + ((((quad << 1))     ^ e) << 2)];
      floatx4 f1 = *(const floatx4*)&Asf[(m << 5) + ((((quad << 1) | 1) ^ e) << 2)];
      bf16x8 o;
      o[0] = (bf16_t)f0[0]; o[1] = (bf16_t)f0[1];
      o[2] = (bf16_t)f0[2]; o[3] = (bf16_t)f0[3];
      o[4] = (bf16_t)f1[0]; o[5] = (bf16_t)f1[1];
      o[6] = (bf16_t)f1[2]; o[7] = (bf16_t)f1[3];
      af[mi] = o;
    }
#pragma unroll
    for (int ni = 0; ni < 4; ni++) {
      int n = wx + ni * 16 + l15;
      bfv[ni] = *(const bf16x8*)&Bs[n * 32 + ((quad ^ (n & 3)) << 3)];
    }
#pragma unroll
    for (int mi = 0; mi < 4; mi++)
#pragma unroll
      for (int ni = 0; ni < 4; ni++)
        acc[mi][ni] = __builtin_amdgcn_mfma_f32_16x16x32_bf16(
            af[mi], bfv[ni], acc[mi][ni], 0, 0, 0);
  }

  const float* bias = z == 0 ? bq : (z == 1 ? bk : bv);
  bf16_t* outp      = z == 0 ? qo : (z == 1 ? ko : vo);
  const float scl   = (z == 0) ? QSCALE : 1.0f;
#pragma unroll
  for (int mi = 0; mi < 4; mi++) {
#pragma unroll
    for (int ni = 0; ni < 4; ni++) {
      const int nn = (n0g + wx + ni * 16 + l15) & (D_MODEL - 1);
      const float bvv = bias[nn];
      const int h = nn >> 6, d = nn & 63;
#pragma unroll
      for (int r = 0; r < 4; r++) {
        const int m = m0 + wy + mi * 16 + quad * 4 + r;
        const int b = m >> 11, srow = m & (S_LEN - 1);
        float v = (acc[mi][ni][r] + bvv) * scl;
        if (z < 2) {
          outp[((((size_t)(b * NHEAD + h) << 11) + srow) << 6) + d] = (bf16_t)v;
        } else {
          outp[((((size_t)(b * NHEAD + h) << 6) + d) << 11) + srow] = (bf16_t)v;
        }
      }
    }
  }
}

// ---------------------------------------------------------------------------
// Output GEMM: out = obuf(bf16) @ Wo + bo, fp32 out. Dual global_load_lds.
// (round-0 proven serial form)
// ---------------------------------------------------------------------------
__global__ __launch_bounds__(256)
void out_gemm_kernel(const bf16_t* __restrict__ A, const bf16_t* __restrict__ Wt,
                     const float* __restrict__ bias, float* __restrict__ out)
{
  __shared__ bf16_t As[128 * 32];
  __shared__ bf16_t Bs[128 * 32];
  const int L = blockIdx.x + 8 * blockIdx.y;      // 0..511
  const int n0 = (((L >> 3) & 7)) << 7;
  const int m0 = ((((L >> 6) << 3) | (L & 7))) << 7;
  const int tid = threadIdx.x;
  const int lane = tid & 63;
  const int w = tid >> 6;
  const int l15 = lane & 15;
  const int quad = lane >> 4;
  const int wy = (w >> 1) << 6;
  const int wx = (w & 1) << 6;
  const int w64 = w << 6;

  floatx4 acc[4][4];
#pragma unroll
  for (int i = 0; i < 4; i++)
#pragma unroll
    for (int jj = 0; jj < 4; jj++)
#pragma unroll
      for (int r = 0; r < 4; r++) acc[i][jj][r] = 0.0f;

  for (int kt = 0; kt < 32; kt++) {
    const int k0 = kt << 5;
    __syncthreads();
#pragma unroll
    for (int p = 0; p < 2; p++) {
      int slot = p * 256 + w64 + lane;
      int row = slot >> 2;
      int kc = (slot & 3) ^ (row & 3);
      load_lds16(&A[(size_t)(m0 + row) * D_MODEL + k0 + (kc << 3)],
                 &As[(size_t)(p * 256 + w64) << 3]);
      load_lds16(&Wt[(size_t)(n0 + row) * D_MODEL + k0 + (kc << 3)],
                 &Bs[(size_t)(p * 256 + w64) << 3]);
    }
    __syncthreads();

    bf16x8 af[4], bfv[4];
#pragma unroll
    for (int mi = 0; mi < 4; mi++) {
      int m = wy + mi * 16 + l15;
      af[mi] = *(const bf16x8*)&As[m * 32 + ((quad ^ (m & 3)) << 3)];
    }
#pragma unroll
    for (int ni = 0; ni < 4; ni++) {
      int n = wx + ni * 16 + l15;
      bfv[ni] = *(const bf16x8*)&Bs[n * 32 + ((quad ^ (n & 3)) << 3)];
    }
#pragma unroll
    for (int mi = 0; mi < 4; mi++)
#pragma unroll
      for (int ni = 0; ni < 4; ni++)
        acc[mi][ni] = __builtin_amdgcn_mfma_f32_16x16x32_bf16(
            af[mi], bfv[ni], acc[mi][ni], 0, 0, 0);
  }

#pragma unroll
  for (int mi = 0; mi < 4; mi++) {
#pragma unroll
    for (int ni = 0; ni < 4; ni++) {
      const int nbase = n0 + wx + ni * 16 + l15;
      const float bv = bias[nbase];
#pragma unroll
      for (int r = 0; r < 4; r++) {
        const int m = m0 + wy + mi * 16 + quad * 4 + r;
        out[((size_t)m << 10) + nbase] = acc[mi][ni][r] + bv;
      }
    }
  }
}

// ---------------------------------------------------------------------------
// Causal flash attention, S^T formulation, BALANCED pairing (r5-verified).
// Round-4 changes: (1) XCD-clustering block remap — all 16 pair-blocks of a
// head land on one XCD (lin%8 invariant per bh), so K/V (512KB/head) become
// L2-resident; (2) setprio(1) around MFMA clusters (T5); (3) defer-max
// rescale skip, THR=5 in exp2 domain (T13).
// ---------------------------------------------------------------------------
__global__ __launch_bounds__(256, 4)
void attn_kernel(const bf16_t* __restrict__ qp, const bf16_t* __restrict__ kp,
                 const bf16_t* __restrict__ vtp, bf16_t* __restrict__ ob)
{
  __shared__ bf16_t Kt0[64 * 64];
  __shared__ bf16_t Kt1[64 * 64];
  __shared__ bf16_t Vt0[64 * 64];
  __shared__ bf16_t Vt1[64 * 64];

  // XCD-clustering decode: lin%8 == bh%8 for all 16 pairs of a head.
  // Bijective: lin(10b) <-> {xcd(3b)=bh&7, pair(4b), bh>>3(3b)}.
  const int lin = blockIdx.x + (blockIdx.y << 4);   // 0..1023
  const int pair = (lin >> 3) & 15;                 // 0..15
  const int bh = (lin & 7) | ((lin >> 7) << 3);     // 0..63
  const int tid = threadIdx.x;
  const int w = tid >> 6;
  const int lane = tid & 63;
  const int l15 = lane & 15;
  const int quad = lane >> 4;

  const bf16_t* Qh = qp + ((size_t)bh << 17);
  const bf16_t* Kh = kp + ((size_t)bh << 17);
  const bf16_t* Vh = vtp + ((size_t)bh << 17);   // [64][2048]
  const int b = bh >> 4, h = bh & 15;

  auto stage = [&](int k0s, bf16_t* dK, bf16_t* dV) {
#pragma unroll
    for (int p = 0; p < 2; p++) {
      const int sbase = (w << 7) + (p << 6);
      const int slot = sbase + lane;
      const int row = slot >> 3;
      const int c = (slot & 7) ^ (row & 7);
      load_lds16(&Kh[((size_t)(k0s + row) << 6) + (c << 3)], &dK[sbase << 3]);
      load_lds16(&Vh[((size_t)row << 11) + k0s + (c << 3)], &dV[sbase << 3]);
    }
  };

  int par = 0;   // global tile-counter parity: current buffer index

  auto phase = [&](int qt, bool prefetch_next_phase) {
    const int q0 = qt << 6;
    const int qbase = q0 + (w << 4);       // wave's 16 q-rows
    const int nkb = qt + 1;

    bf16x8 qf[2];
#pragma unroll
    for (int ks = 0; ks < 2; ks++)
      qf[ks] = *(const bf16x8*)&Qh[(size_t)(qbase + l15) * DK +
                                   ks * 32 + (quad << 3)];

    floatx4 acc_o[4];
    float m_i = -1e30f, l_i = 0.0f;
#pragma unroll
    for (int nd = 0; nd < 4; nd++)
#pragma unroll
      for (int r = 0; r < 4; r++) acc_o[nd][r] = 0.0f;

    for (int kb = 0; kb < nkb; kb++) {
      const int k0 = kb << 6;
      __syncthreads();   // drains this tile's gll (issued one body ago)

      const bf16_t* cK = par ? Kt1 : Kt0;
      const bf16_t* cV = par ? Vt1 : Vt0;
      bf16_t* nK = par ? Kt0 : Kt1;
      bf16_t* nV = par ? Vt0 : Vt1;

      if (kb + 1 < nkb)             stage((kb + 1) << 6, nK, nV);
      else if (prefetch_next_phase) stage(0, nK, nV);

      bf16x8 bk[2][4];
#pragma unroll
      for (int ks = 0; ks < 2; ks++)
#pragma unroll
        for (int ni = 0; ni < 4; ni++) {
          const int row = ni * 16 + l15;
          const int cp = ((ks << 2) + quad) ^ (row & 7);
          bk[ks][ni] = *(const bf16x8*)&cK[(row << 6) + (cp << 3)];
        }

      floatx4 st[4];
#pragma unroll
      for (int ni = 0; ni < 4; ni++)
#pragma unroll
        for (int r = 0; r < 4; r++) st[ni][r] = 0.0f;
      __builtin_amdgcn_s_setprio(1);
#pragma unroll
      for (int ks = 0; ks < 2; ks++)
#pragma unroll
        for (int ni = 0; ni < 4; ni++)
          st[ni] = __builtin_amdgcn_mfma_f32_16x16x32_bf16(
              bk[ks][ni], qf[ks], st[ni], 0, 0, 0);
      __builtin_amdgcn_s_setprio(0);

      if (k0 + 63 > qbase) {
        const int qrow = qbase + l15;
#pragma unroll
        for (int ni = 0; ni < 4; ni++) {
          const int keyb = k0 + ni * 16 + quad * 4;
#pragma unroll
          for (int r = 0; r < 4; r++)
            if (keyb + r > qrow) st[ni][r] = -1e30f;
        }
      }

      float v = st[0][0];
#pragma unroll
      for (int ni = 0; ni < 4; ni++)
#pragma unroll
        for (int r = 0; r < 4; r++) v = fmaxf(v, st[ni][r]);
      v = fmaxf(v, __shfl_xor(v, 16));
      v = fmaxf(v, __shfl_xor(v, 32));

      // Defer-max (T13): skip rescale when tile max doesn't grow past THR.
      // P then bounded by 2^5 = 32; bf16 relative precision unaffected.
      if (!__all(v <= m_i + 5.0f)) {
        const float mn = fmaxf(m_i, v);
        const float alpha = __builtin_amdgcn_exp2f(m_i - mn);
        m_i = mn;
        l_i *= alpha;
#pragma unroll
        for (int r = 0; r < 4; r++) {
          float ab = bperm_f((quad * 4 + r) << 2, alpha);
#pragma unroll
          for (int nd = 0; nd < 4; nd++) acc_o[nd][r] *= ab;
        }
      }

      unsigned pd[4][2];
      float ssum = 0.0f;
#pragma unroll
      for (int c = 0; c < 4; c++)
#pragma unroll
        for (int hh = 0; hh < 2; hh++) {
          float p0 = __builtin_amdgcn_exp2f(st[c][2 * hh]     - m_i);
          float p1 = __builtin_amdgcn_exp2f(st[c][2 * hh + 1] - m_i);
          ssum += p0 + p1;
          pd[c][hh] = pack_bf16(p0, p1);
        }
      ssum += __shfl_xor(ssum, 16);
      ssum += __shfl_xor(ssum, 32);
      l_i += ssum;

      union AV { unsigned u[4]; bf16x8 v; };
      AV av[2];
#pragma unroll
      for (int ks = 0; ks < 2; ks++)
#pragma unroll
        for (int i = 0; i < 4; i++) {
          const int addr = ((((2 * quad + (i >> 1)) & 3) << 4) | l15) << 2;
          int lo = __builtin_amdgcn_ds_bpermute(addr, (int)pd[ks * 2][i & 1]);
          int hi = __builtin_amdgcn_ds_bpermute(addr, (int)pd[ks * 2 + 1][i & 1]);
          av[ks].u[i] = (unsigned)(quad >= 2 ? hi : lo);
        }

#pragma unroll
      for (int ks = 0; ks < 2; ks++) {
        bf16x8 bvv[4];
#pragma unroll
        for (int nd = 0; nd < 4; nd++) {
          const int row = nd * 16 + l15;
          const int cp = ((ks << 2) + quad) ^ (row & 7);
          bvv[nd] = *(const bf16x8*)&cV[(row << 6) + (cp << 3)];
        }
        __builtin_amdgcn_s_setprio(1);
#pragma unroll
        for (int nd = 0; nd < 4; nd++)
          acc_o[nd] = __builtin_amdgcn_mfma_f32_16x16x32_bf16(
              av[ks].v, bvv[nd], acc_o[nd], 0, 0, 0);
        __builtin_amdgcn_s_setprio(0);
      }

      par ^= 1;
    }

    const float inv = 1.0f / l_i;
#pragma unroll
    for (int r = 0; r < 4; r++) {
      const float linv = bperm_f((quad * 4 + r) << 2, inv);
      const int sRow = qbase + quad * 4 + r;
#pragma unroll
      for (int nd = 0; nd < 4; nd++) {
        const int d = nd * 16 + l15;
        ob[(((size_t)(b * S_LEN + sRow)) << 10) + h * 64 + d] =
            (bf16_t)(acc_o[nd][r] * linv);
      }
    }
  };

  stage(0, Kt0, Vt0);            // tile 0 of phase A into buffer 0
  phase(31 - pair, true);        // big tile first; prefetch B's tile 0 at seam
  phase(pair, false);            // total bodies = (32-p) + (p+1) = 33, uniform
}

// ---------------------------------------------------------------------------
extern "C" void kernel_launch(void* const* d_in, const int* in_sizes, int n_in,
                              void* d_out, int out_size, void* d_ws, size_t ws_size,
                              hipStream_t stream)
{
  (void)in_sizes; (void)n_in; (void)out_size;
  const float* Q  = (const float*)d_in[0];
  const float* K  = (const float*)d_in[1];
  const float* V  = (const float*)d_in[2];
  const float* Wq = (const float*)d_in[4];
  const float* bq = (const float*)d_in[5];
  const float* Wk = (const float*)d_in[6];
  const float* bk = (const float*)d_in[7];
  const float* Wv = (const float*)d_in[8];
  const float* bv = (const float*)d_in[9];
  const float* Wo = (const float*)d_in[10];
  const float* bo = (const float*)d_in[11];
  float* out = (float*)d_out;

  const size_t NELT = (size_t)MROWS * D_MODEL;        // 8 Mi elements
  const size_t WELT = (size_t)D_MODEL * D_MODEL;      // 1 Mi elements

  // New layout (104 MB): qp|kp|vtp (48MB) | weights (8MB) | abf (48MB).
  // obuf ALIASES abf (abf dead after qkv8; obuf born after).
  const size_t need_new = (3 * NELT + 4 * WELT + 3 * NELT) * sizeof(bf16_t);

  bf16_t* qp   = (bf16_t*)d_ws;
  bf16_t* kp   = qp + NELT;
  bf16_t* vtp  = kp + NELT;
  bf16_t* wqt  = vtp + NELT;
  bf16_t* wkt  = wqt + WELT;
  bf16_t* wvt  = wkt + WELT;
  bf16_t* wot  = wvt + WELT;
  bf16_t* abf  = wot + WELT;       // [3][8192][1024] bf16 (new path only)
  bf16_t* obuf = abf;              // alias: lives in abf's first 16MB

  dim3 blk(256);
  transpose_w_kernel<<<dim3(16, 16, 4), blk, 0, stream>>>(
      Wq, Wk, Wv, Wo, wqt, wkt, wvt, wot);

  if (ws_size >= need_new) {
    convert_a_kernel<<<dim3(MROWS * D_MODEL / (256 * 8), 3), blk, 0, stream>>>(
        Q, K, V, abf);
    qkv8_kernel<<<dim3((MROWS / 256) * (3 * D_MODEL / 256)), dim3(512), 0,
                  stream>>>(abf, wqt, bq, bk, bv, qp, kp, vtp);
  } else {
    // Fallback (72 MB, round-0 verified): obuf sits where abf would start.
    qkv_legacy_kernel<<<dim3(3 * D_MODEL / 128, MROWS / 128), blk, 0, stream>>>(
        Q, K, V, wqt, bq, bk, bv, qp, kp, vtp);
  }

  attn_kernel<<<dim3(16, BATCH * NHEAD), blk, 0, stream>>>(qp, kp, vtp, obuf);

  out_gemm_kernel<<<dim3(D_MODEL / 128, MROWS / 128), blk, 0, stream>>>(
      obuf, wot, bo, out);
}

// Round 6
// 361.351 us; speedup vs baseline: 1.0978x; 1.0032x over previous
//
#include <hip/hip_runtime.h>

typedef __bf16 bf16_t;
typedef __bf16 bf16x8 __attribute__((ext_vector_type(8)));
typedef __bf16 bf16x4 __attribute__((ext_vector_type(4)));
typedef float  floatx4 __attribute__((ext_vector_type(4)));

#define D_MODEL 1024
#define S_LEN   2048
#define NHEAD   16
#define DK      64
#define BATCH   4
#define MROWS   (BATCH * S_LEN)   // 8192
// 1/sqrt(64) * log2(e): fold into Q so scores arrive in exp2 domain
#define QSCALE  0.18033688011112042f

__device__ __forceinline__ void load_lds16(const void* gsrc, void* ldst) {
  __builtin_amdgcn_global_load_lds(
      (const __attribute__((address_space(1))) void*)gsrc,
      (__attribute__((address_space(3))) void*)ldst, 16, 0, 0);
}

__device__ __forceinline__ unsigned pack_bf16(float a, float b) {
  union { bf16_t h[2]; unsigned u; } t;
  t.h[0] = (bf16_t)a; t.h[1] = (bf16_t)b;
  return t.u;
}

__device__ __forceinline__ float bperm_f(int addr, float v) {
  union { float f; int i; } in, out;
  in.f = v;
  out.i = __builtin_amdgcn_ds_bpermute(addr, in.i);
  return out.f;
}

__device__ __forceinline__ void barrier_mem() {
  asm volatile("" ::: "memory");
  __builtin_amdgcn_s_barrier();
  asm volatile("" ::: "memory");
}

// ---------------------------------------------------------------------------
// fp32 -> bf16 convert of the three activation inputs into one [3][8192][1024]
// contiguous bf16 buffer (A operand of the 8-phase QKV GEMM).
// ---------------------------------------------------------------------------
__global__ __launch_bounds__(256)
void convert_a_kernel(const float* __restrict__ Q, const float* __restrict__ K,
                      const float* __restrict__ V, bf16_t* __restrict__ Abf)
{
  const int z = blockIdx.y;
  const float* src = z == 0 ? Q : (z == 1 ? K : V);
  bf16_t* dst = Abf + ((size_t)z << 23);          // z * 8192 * 1024
  const size_t off = ((size_t)blockIdx.x * 256 + threadIdx.x) * 8;
  floatx4 a = *(const floatx4*)&src[off];
  floatx4 b = *(const floatx4*)&src[off + 4];
  bf16x8 o;
  o[0] = (bf16_t)a[0]; o[1] = (bf16_t)a[1];
  o[2] = (bf16_t)a[2]; o[3] = (bf16_t)a[3];
  o[4] = (bf16_t)b[0]; o[5] = (bf16_t)b[1];
  o[6] = (bf16_t)b[2]; o[7] = (bf16_t)b[3];
  *(bf16x8*)&dst[off] = o;
}

// ---------------------------------------------------------------------------
// Fused weight transpose + fp32->bf16 for all 4 weights (z selects).
// wqt/wkt/wvt are contiguous -> form a [3072][1024] matrix for the QKV GEMM.
// ---------------------------------------------------------------------------
__global__ __launch_bounds__(256)
void transpose_w_kernel(const float* __restrict__ W0, const float* __restrict__ W1,
                        const float* __restrict__ W2, const float* __restrict__ W3,
                        bf16_t* __restrict__ T0, bf16_t* __restrict__ T1,
                        bf16_t* __restrict__ T2, bf16_t* __restrict__ T3)
{
  const int z = blockIdx.z;
  const float* W = z == 0 ? W0 : (z == 1 ? W1 : (z == 2 ? W2 : W3));
  bf16_t* Wt     = z == 0 ? T0 : (z == 1 ? T1 : (z == 2 ? T2 : T3));

  __shared__ float tile[64][65];
  const int x0 = blockIdx.x * 64;         // n
  const int y0 = blockIdx.y * 64;         // k
  const int tid = threadIdx.x;
  const int r = tid >> 4;
  const int c = (tid & 15) << 2;
#pragma unroll
  for (int p = 0; p < 4; p++) {
    floatx4 v = *(const floatx4*)&W[(size_t)(y0 + p * 16 + r) * D_MODEL + x0 + c];
    tile[p * 16 + r][c + 0] = v[0];
    tile[p * 16 + r][c + 1] = v[1];
    tile[p * 16 + r][c + 2] = v[2];
    tile[p * 16 + r][c + 3] = v[3];
  }
  __syncthreads();
#pragma unroll
  for (int p = 0; p < 4; p++) {
    int row = p * 16 + r;
    bf16x4 o;
    o[0] = (bf16_t)tile[c + 0][row];
    o[1] = (bf16_t)tile[c + 1][row];
    o[2] = (bf16_t)tile[c + 2][row];
    o[3] = (bf16_t)tile[c + 3][row];
    *(bf16x4*)&Wt[(size_t)(x0 + row) * D_MODEL + y0 + c] = o;
  }
}

// ---------------------------------------------------------------------------
// QKV projection, BM=128 x BN=256 8-phase GEMM (T2+T3+T4+T5).
//   M=8192, N=3072, K=1024, BK=64. Grid 768 blocks = 3.0 exact rounds over
//   256 CUs (fixes the 1.5-round tail of the 256x256 version).
//   512 threads = 8 waves (2M x 4N); wave tile 64x64 = acc[4][4]; 8 MFMA/ph.
//   LDS 96 KiB: lds[2][3][128*64] = [buf][A,B0,B1]. XOR swizzle c^(row&7)
//   on BOTH gll source chunk and ds_read (involution; round-4-verified pair).
//   HALF-LIVENESS (wave-indexed reads; the round-5 lesson):
//     A (single half) read at RDA phases {0,2} / {4,6}; B halves (wave-split
//     wn>>1) read at RDB phases {0,1,3} / {4,5,7}. Quadrant order
//     (0,0),(0,1),(1,1),(1,0) -> RDA=1,0,1,0 RDB=1,1,0,1.
//   Stage slots (iteration it; u=2it in buf0 @ph0-3, v=2it+1 in buf1 @ph4-7):
//     ph0: buf1.B0(v)  ph1: buf1.B1(v)  ph3: buf0.A(u+2) +vmcnt(2)
//     ph4: buf0.B0(u+2) ph5: buf0.B1(u+2) ph7: buf1.A(v+2) +vmcnt(2)
//   Every stage issues >=1 barrier after its half's group-final read; vmcnt(2)
//   at ph3 forces {A(v),B0(v),B1(v)} landed (distances 4/3/2 phases) before
//   ph4; ph7 symmetric for buf0(u+2) before next ph0. Never drains below 2.
//   Tail stages wrap (&15): harmless re-stage.
// ---------------------------------------------------------------------------
__global__ __launch_bounds__(512, 2)
void qkv8_kernel(const bf16_t* __restrict__ Abf, const bf16_t* __restrict__ Wcat,
                 const float* __restrict__ bq, const float* __restrict__ bk,
                 const float* __restrict__ bv,
                 bf16_t* __restrict__ qo, bf16_t* __restrict__ ko,
                 bf16_t* __restrict__ vo)
{
  __shared__ bf16_t lds[2][3][128 * 64];   // 98304 B

  // Bijective XCD swizzle: 768 blocks, 8 XCDs x 96 (bm-major within XCD:
  // 8 bm-rows x 12 bn -> A panels reused 12x inside one XCD's L2).
  const int orig = blockIdx.x;                 // 0..767
  const int L = (orig & 7) * 96 + (orig >> 3);
  const int bm = L / 12, bn = L % 12;          // bm 0..63, bn 0..11
  const int m0 = bm << 7;                      // BM=128
  const int n0 = bn << 8;                      // BN=256
  const int z  = n0 >> 10;                     // projection (block-uniform)
  const bf16_t* A = Abf + ((size_t)z << 23);

  const int tid = threadIdx.x;
  const int wid = tid >> 6, lane = tid & 63;
  const int l15 = lane & 15, quad = lane >> 4;
  const int wm = wid >> 2, wn = wid & 3;

  floatx4 acc[4][4] = {};
  bf16x8 Af[2][2], Bf[2][2];

  // half id: 0=A (rows m0..m0+127), 1=B0 (n0..n0+127), 2=B1 (n0+128..+255)
  auto stage_half = [&](int buf, int half, int kt) {
    const bf16_t* src = half == 0
        ? (A + (size_t)m0 * D_MODEL)
        : (Wcat + (size_t)(n0 + ((half - 1) << 7)) * D_MODEL);
    const int k0 = (kt & 15) << 6;
    bf16_t* dst = &lds[buf][half][0];
#pragma unroll
    for (int p = 0; p < 2; p++) {
      const int slot = (p << 9) + tid;         // 0..1023
      const int row = slot >> 3;               // 0..127
      const int c = (slot & 7) ^ (row & 7);    // pre-swizzled source chunk
      load_lds16(&src[(size_t)row * D_MODEL + k0 + (c << 3)],
                 &dst[(size_t)((p << 9) + (wid << 6)) << 3]);
    }
  };

#define PHASE(BUF, MH, NH, RDA, RDB, DOST, SBUF, SHALF, SKT, VMW)              \
  {                                                                            \
    if (RDA) {                                                                 \
      _Pragma("unroll") for (int mi = 0; mi < 2; mi++) {                       \
        const int row = (wm << 6) + (((MH) * 2 + mi) << 4) + l15;              \
        _Pragma("unroll") for (int ks = 0; ks < 2; ks++) {                     \
          const int ck = (ks << 2) + quad;                                     \
          Af[mi][ks] = *(const bf16x8*)&lds[BUF][0]                            \
              [(row << 6) + ((ck ^ (row & 7)) << 3)];                          \
        }                                                                      \
      }                                                                        \
    }                                                                          \
    if (RDB) {                                                                 \
      _Pragma("unroll") for (int ni = 0; ni < 2; ni++) {                       \
        const int row = ((wn & 1) << 6) + (((NH) * 2 + ni) << 4) + l15;        \
        _Pragma("unroll") for (int ks = 0; ks < 2; ks++) {                     \
          const int ck = (ks << 2) + quad;                                     \
          Bf[ni][ks] = *(const bf16x8*)&lds[BUF][1 + (wn >> 1)]                \
              [(row << 6) + ((ck ^ (row & 7)) << 3)];                          \
        }                                                                      \
      }                                                                        \
    }                                                                          \
    if (DOST) stage_half(SBUF, SHALF, SKT);                                    \
    barrier_mem();                                                             \
    __builtin_amdgcn_s_setprio(1);                                             \
    _Pragma("unroll") for (int mi = 0; mi < 2; mi++)                           \
      _Pragma("unroll") for (int ni = 0; ni < 2; ni++)                         \
        _Pragma("unroll") for (int ks = 0; ks < 2; ks++)                       \
          acc[(MH) * 2 + mi][(NH) * 2 + ni] =                                  \
              __builtin_amdgcn_mfma_f32_16x16x32_bf16(                         \
                  Af[mi][ks], Bf[ni][ks],                                      \
                  acc[(MH) * 2 + mi][(NH) * 2 + ni], 0, 0, 0);                 \
    __builtin_amdgcn_s_setprio(0);                                             \
    if (VMW) asm volatile("s_waitcnt vmcnt(2)" ::: "memory");                  \
    barrier_mem();                                                             \
  }

  // Prologue: buf0 <- tile0 (A,B0,B1); buf1.A <- tile1 (stays in flight).
  stage_half(0, 0, 0);
  stage_half(0, 1, 0);
  stage_half(0, 2, 0);
  stage_half(1, 0, 1);
  asm volatile("s_waitcnt vmcnt(2)" ::: "memory");
  barrier_mem();

  for (int it = 0; it < 8; it++) {
    const int tv  = 2 * it + 1;          // buf1 tile (read ph4-7)
    const int tu2 = 2 * it + 2;          // next buf0 tile
    const int tv2 = 2 * it + 3;          // next buf1 tile
    PHASE(0, 0, 0, 1, 1, 1, 1, 1, tv,  0)   // stage buf1.B0(v)
    PHASE(0, 0, 1, 0, 1, 1, 1, 2, tv,  0)   // stage buf1.B1(v)
    PHASE(0, 1, 1, 1, 0, 0, 0, 0, 0,   0)   // free slot
    PHASE(0, 1, 0, 0, 1, 1, 0, 0, tu2, 1)   // stage buf0.A(u+2); vmcnt(2)
    PHASE(1, 0, 0, 1, 1, 1, 0, 1, tu2, 0)   // stage buf0.B0(u+2)
    PHASE(1, 0, 1, 0, 1, 1, 0, 2, tu2, 0)   // stage buf0.B1(u+2)
    PHASE(1, 1, 1, 1, 0, 0, 0, 0, 0,   0)   // free slot
    PHASE(1, 1, 0, 0, 1, 1, 1, 0, tv2, 1)   // stage buf1.A(v+2); vmcnt(2)
  }
  asm volatile("s_waitcnt vmcnt(0)" ::: "memory");  // drain tail stages

#undef PHASE

  const float* bias = z == 0 ? bq : (z == 1 ? bk : bv);
  bf16_t* outp      = z == 0 ? qo : (z == 1 ? ko : vo);
  const float scl   = (z == 0) ? QSCALE : 1.0f;
#pragma unroll
  for (int mi = 0; mi < 4; mi++) {
#pragma unroll
    for (int ni = 0; ni < 4; ni++) {
      const int nn = (n0 + (wn << 6) + (ni << 4) + l15) & (D_MODEL - 1);
      const float bvv = bias[nn];
      const int h = nn >> 6, d = nn & 63;
#pragma unroll
      for (int r = 0; r < 4; r++) {
        const int m = m0 + (wm << 6) + (mi << 4) + quad * 4 + r;
        const int b = m >> 11, srow = m & (S_LEN - 1);
        float v = (acc[mi][ni][r] + bvv) * scl;
        if (z < 2) {
          outp[((((size_t)(b * NHEAD + h) << 11) + srow) << 6) + d] = (bf16_t)v;
        } else {
          outp[((((size_t)(b * NHEAD + h) << 6) + d) << 11) + srow] = (bf16_t)v;
        }
      }
    }
  }
}

// ---------------------------------------------------------------------------
// LEGACY QKV (round-0 verified, 24 KB LDS, serial staging) — fallback when
// ws_size cannot hold the bf16 A buffer. Reads fp32 A directly.
// ---------------------------------------------------------------------------
__global__ __launch_bounds__(256, 3)
void qkv_legacy_kernel(const float* __restrict__ Qi, const float* __restrict__ Ki,
                       const float* __restrict__ Vi, const bf16_t* __restrict__ Wcat,
                       const float* __restrict__ bq, const float* __restrict__ bk,
                       const float* __restrict__ bv,
                       bf16_t* __restrict__ qo, bf16_t* __restrict__ ko,
                       bf16_t* __restrict__ vo)
{
  __shared__ float  Asf[128 * 32];
  __shared__ bf16_t Bs[128 * 32];

  const int L = blockIdx.x + 24 * blockIdx.y;
  const int j = (L >> 3) & 7;
  const int s = ((L >> 6) << 3) | (L & 7);
  const int z = s >> 6;
  const int n0g = (((z << 3) | j)) << 7;
  const int m0 = (s & 63) << 7;

  const float* A = z == 0 ? Qi : (z == 1 ? Ki : Vi);

  const int tid = threadIdx.x;
  const int lane = tid & 63;
  const int w = tid >> 6;
  const int l15 = lane & 15;
  const int quad = lane >> 4;
  const int wy = (w >> 1) << 6;
  const int wx = (w & 1) << 6;
  const int w64 = w << 6;

  floatx4 acc[4][4];
#pragma unroll
  for (int i = 0; i < 4; i++)
#pragma unroll
    for (int jj = 0; jj < 4; jj++)
#pragma unroll
      for (int r = 0; r < 4; r++) acc[i][jj][r] = 0.0f;

  for (int kt = 0; kt < 32; kt++) {
    const int k0 = kt << 5;
    __syncthreads();
#pragma unroll
    for (int p = 0; p < 2; p++) {
      int slot = p * 256 + w64 + lane;
      int row = slot >> 2;
      int kc = (slot & 3) ^ (row & 3);
      load_lds16(&Wcat[(size_t)(n0g + row) * D_MODEL + k0 + (kc << 3)],
                 &Bs[(size_t)(p * 256 + w64) << 3]);
    }
#pragma unroll
    for (int p = 0; p < 4; p++) {
      int sbase = (w << 8) + (p << 6);
      int slot = sbase + lane;
      int row = slot >> 3;
      int ca = (slot & 7) ^ (row & 7);
      load_lds16(&A[(size_t)(m0 + row) * D_MODEL + k0 + (ca << 2)],
                 &Asf[(size_t)sbase << 2]);
    }
    __syncthreads();

    bf16x8 af[4], bfv[4];
#pragma unroll
    for (int mi = 0; mi < 4; mi++) {
      const int m = wy + mi * 16 + l15;
      const int e = m & 7;
      floatx4 f0 = *(const floatx4*)&Asf[(m << 5) + ((((quad << 1))     ^ e) << 2)];
      floatx4 f1 = *(const floatx4*)&Asf[(m << 5) + ((((quad << 1) | 1) ^ e) << 2)];
      bf16x8 o;
      o[0] = (bf16_t)f0[0]; o[1] = (bf16_t)f0[1];
      o[2] = (bf16_t)f0[2]; o[3] = (bf16_t)f0[3];
      o[4] = (bf16_t)f1[0]; o[5] = (bf16_t)f1[1];
      o[6] = (bf16_t)f1[2]; o[7] = (bf16_t)f1[3];
      af[mi] = o;
    }
#pragma unroll
    for (int ni = 0; ni < 4; ni++) {
      int n = wx + ni * 16 + l15;
      bfv[ni] = *(const bf16x8*)&Bs[n * 32 + ((quad ^ (n & 3)) << 3)];
    }
#pragma unroll
    for (int mi = 0; mi < 4; mi++)
#pragma unroll
      for (int ni = 0; ni < 4; ni++)
        acc[mi][ni] = __builtin_amdgcn_mfma_f32_16x16x32_bf16(
            af[mi], bfv[ni], acc[mi][ni], 0, 0, 0);
  }

  const float* bias = z == 0 ? bq : (z == 1 ? bk : bv);
  bf16_t* outp      = z == 0 ? qo : (z == 1 ? ko : vo);
  const float scl   = (z == 0) ? QSCALE : 1.0f;
#pragma unroll
  for (int mi = 0; mi < 4; mi++) {
#pragma unroll
    for (int ni = 0; ni < 4; ni++) {
      const int nn = (n0g + wx + ni * 16 + l15) & (D_MODEL - 1);
      const float bvv = bias[nn];
      const int h = nn >> 6, d = nn & 63;
#pragma unroll
      for (int r = 0; r < 4; r++) {
        const int m = m0 + wy + mi * 16 + quad * 4 + r;
        const int b = m >> 11, srow = m & (S_LEN - 1);
        float v = (acc[mi][ni][r] + bvv) * scl;
        if (z < 2) {
          outp[((((size_t)(b * NHEAD + h) << 11) + srow) << 6) + d] = (bf16_t)v;
        } else {
          outp[((((size_t)(b * NHEAD + h) << 6) + d) << 11) + srow] = (bf16_t)v;
        }
      }
    }
  }
}

// ---------------------------------------------------------------------------
// Output GEMM: out = obuf(bf16) @ Wo + bo, fp32 out. Dual global_load_lds.
// (round-0 proven serial form; grid 512 = 2.0 exact rounds, no tail issue)
// ---------------------------------------------------------------------------
__global__ __launch_bounds__(256)
void out_gemm_kernel(const bf16_t* __restrict__ A, const bf16_t* __restrict__ Wt,
                     const float* __restrict__ bias, float* __restrict__ out)
{
  __shared__ bf16_t As[128 * 32];
  __shared__ bf16_t Bs[128 * 32];
  const int L = blockIdx.x + 8 * blockIdx.y;      // 0..511
  const int n0 = (((L >> 3) & 7)) << 7;
  const int m0 = ((((L >> 6) << 3) | (L & 7))) << 7;
  const int tid = threadIdx.x;
  const int lane = tid & 63;
  const int w = tid >> 6;
  const int l15 = lane & 15;
  const int quad = lane >> 4;
  const int wy = (w >> 1) << 6;
  const int wx = (w & 1) << 6;
  const int w64 = w << 6;

  floatx4 acc[4][4];
#pragma unroll
  for (int i = 0; i < 4; i++)
#pragma unroll
    for (int jj = 0; jj < 4; jj++)
#pragma unroll
      for (int r = 0; r < 4; r++) acc[i][jj][r] = 0.0f;

  for (int kt = 0; kt < 32; kt++) {
    const int k0 = kt << 5;
    __syncthreads();
#pragma unroll
    for (int p = 0; p < 2; p++) {
      int slot = p * 256 + w64 + lane;
      int row = slot >> 2;
      int kc = (slot & 3) ^ (row & 3);
      load_lds16(&A[(size_t)(m0 + row) * D_MODEL + k0 + (kc << 3)],
                 &As[(size_t)(p * 256 + w64) << 3]);
      load_lds16(&Wt[(size_t)(n0 + row) * D_MODEL + k0 + (kc << 3)],
                 &Bs[(size_t)(p * 256 + w64) << 3]);
    }
    __syncthreads();

    bf16x8 af[4], bfv[4];
#pragma unroll
    for (int mi = 0; mi < 4; mi++) {
      int m = wy + mi * 16 + l15;
      af[mi] = *(const bf16x8*)&As[m * 32 + ((quad ^ (m & 3)) << 3)];
    }
#pragma unroll
    for (int ni = 0; ni < 4; ni++) {
      int n = wx + ni * 16 + l15;
      bfv[ni] = *(const bf16x8*)&Bs[n * 32 + ((quad ^ (n & 3)) << 3)];
    }
#pragma unroll
    for (int mi = 0; mi < 4; mi++)
#pragma unroll
      for (int ni = 0; ni < 4; ni++)
        acc[mi][ni] = __builtin_amdgcn_mfma_f32_16x16x32_bf16(
            af[mi], bfv[ni], acc[mi][ni], 0, 0, 0);
  }

#pragma unroll
  for (int mi = 0; mi < 4; mi++) {
#pragma unroll
    for (int ni = 0; ni < 4; ni++) {
      const int nbase = n0 + wx + ni * 16 + l15;
      const float bv = bias[nbase];
#pragma unroll
      for (int r = 0; r < 4; r++) {
        const int m = m0 + wy + mi * 16 + quad * 4 + r;
        out[((size_t)m << 10) + nbase] = acc[mi][ni][r] + bv;
      }
    }
  }
}

// ---------------------------------------------------------------------------
// Causal flash attention, S^T formulation, BALANCED pairing (r5-verified).
// XCD-clustering remap + setprio + defer-max (round-4 verified).
// ---------------------------------------------------------------------------
__global__ __launch_bounds__(256, 4)
void attn_kernel(const bf16_t* __restrict__ qp, const bf16_t* __restrict__ kp,
                 const bf16_t* __restrict__ vtp, bf16_t* __restrict__ ob)
{
  __shared__ bf16_t Kt0[64 * 64];
  __shared__ bf16_t Kt1[64 * 64];
  __shared__ bf16_t Vt0[64 * 64];
  __shared__ bf16_t Vt1[64 * 64];

  const int lin = blockIdx.x + (blockIdx.y << 4);   // 0..1023
  const int pair = (lin >> 3) & 15;                 // 0..15
  const int bh = (lin & 7) | ((lin >> 7) << 3);     // 0..63
  const int tid = threadIdx.x;
  const int w = tid >> 6;
  const int lane = tid & 63;
  const int l15 = lane & 15;
  const int quad = lane >> 4;

  const bf16_t* Qh = qp + ((size_t)bh << 17);
  const bf16_t* Kh = kp + ((size_t)bh << 17);
  const bf16_t* Vh = vtp + ((size_t)bh << 17);   // [64][2048]
  const int b = bh >> 4, h = bh & 15;

  auto stage = [&](int k0s, bf16_t* dK, bf16_t* dV) {
#pragma unroll
    for (int p = 0; p < 2; p++) {
      const int sbase = (w << 7) + (p << 6);
      const int slot = sbase + lane;
      const int row = slot >> 3;
      const int c = (slot & 7) ^ (row & 7);
      load_lds16(&Kh[((size_t)(k0s + row) << 6) + (c << 3)], &dK[sbase << 3]);
      load_lds16(&Vh[((size_t)row << 11) + k0s + (c << 3)], &dV[sbase << 3]);
    }
  };

  int par = 0;   // global tile-counter parity: current buffer index

  auto phase = [&](int qt, bool prefetch_next_phase) {
    const int q0 = qt << 6;
    const int qbase = q0 + (w << 4);       // wave's 16 q-rows
    const int nkb = qt + 1;

    bf16x8 qf[2];
#pragma unroll
    for (int ks = 0; ks < 2; ks++)
      qf[ks] = *(const bf16x8*)&Qh[(size_t)(qbase + l15) * DK +
                                   ks * 32 + (quad << 3)];

    floatx4 acc_o[4];
    float m_i = -1e30f, l_i = 0.0f;
#pragma unroll
    for (int nd = 0; nd < 4; nd++)
#pragma unroll
      for (int r = 0; r < 4; r++) acc_o[nd][r] = 0.0f;

    for (int kb = 0; kb < nkb; kb++) {
      const int k0 = kb << 6;
      __syncthreads();   // drains this tile's gll (issued one body ago)

      const bf16_t* cK = par ? Kt1 : Kt0;
      const bf16_t* cV = par ? Vt1 : Vt0;
      bf16_t* nK = par ? Kt0 : Kt1;
      bf16_t* nV = par ? Vt0 : Vt1;

      if (kb + 1 < nkb)             stage((kb + 1) << 6, nK, nV);
      else if (prefetch_next_phase) stage(0, nK, nV);

      bf16x8 bk[2][4];
#pragma unroll
      for (int ks = 0; ks < 2; ks++)
#pragma unroll
        for (int ni = 0; ni < 4; ni++) {
          const int row = ni * 16 + l15;
          const int cp = ((ks << 2) + quad) ^ (row & 7);
          bk[ks][ni] = *(const bf16x8*)&cK[(row << 6) + (cp << 3)];
        }

      floatx4 st[4];
#pragma unroll
      for (int ni = 0; ni < 4; ni++)
#pragma unroll
        for (int r = 0; r < 4; r++) st[ni][r] = 0.0f;
      __builtin_amdgcn_s_setprio(1);
#pragma unroll
      for (int ks = 0; ks < 2; ks++)
#pragma unroll
        for (int ni = 0; ni < 4; ni++)
          st[ni] = __builtin_amdgcn_mfma_f32_16x16x32_bf16(
              bk[ks][ni], qf[ks], st[ni], 0, 0, 0);
      __builtin_amdgcn_s_setprio(0);

      if (k0 + 63 > qbase) {
        const int qrow = qbase + l15;
#pragma unroll
        for (int ni = 0; ni < 4; ni++) {
          const int keyb = k0 + ni * 16 + quad * 4;
#pragma unroll
          for (int r = 0; r < 4; r++)
            if (keyb + r > qrow) st[ni][r] = -1e30f;
        }
      }

      float v = st[0][0];
#pragma unroll
      for (int ni = 0; ni < 4; ni++)
#pragma unroll
        for (int r = 0; r < 4; r++) v = fmaxf(v, st[ni][r]);
      v = fmaxf(v, __shfl_xor(v, 16));
      v = fmaxf(v, __shfl_xor(v, 32));

      // Defer-max (T13): skip rescale when tile max doesn't grow past THR.
      if (!__all(v <= m_i + 5.0f)) {
        const float mn = fmaxf(m_i, v);
        const float alpha = __builtin_amdgcn_exp2f(m_i - mn);
        m_i = mn;
        l_i *= alpha;
#pragma unroll
        for (int r = 0; r < 4; r++) {
          float ab = bperm_f((quad * 4 + r) << 2, alpha);
#pragma unroll
          for (int nd = 0; nd < 4; nd++) acc_o[nd][r] *= ab;
        }
      }

      unsigned pd[4][2];
      float ssum = 0.0f;
#pragma unroll
      for (int c = 0; c < 4; c++)
#pragma unroll
        for (int hh = 0; hh < 2; hh++) {
          float p0 = __builtin_amdgcn_exp2f(st[c][2 * hh]     - m_i);
          float p1 = __builtin_amdgcn_exp2f(st[c][2 * hh + 1] - m_i);
          ssum += p0 + p1;
          pd[c][hh] = pack_bf16(p0, p1);
        }
      ssum += __shfl_xor(ssum, 16);
      ssum += __shfl_xor(ssum, 32);
      l_i += ssum;

      union AV { unsigned u[4]; bf16x8 v; };
      AV av[2];
#pragma unroll
      for (int ks = 0; ks < 2; ks++)
#pragma unroll
        for (int i = 0; i < 4; i++) {
          const int addr = ((((2 * quad + (i >> 1)) & 3) << 4) | l15) << 2;
          int lo = __builtin_amdgcn_ds_bpermute(addr, (int)pd[ks * 2][i & 1]);
          int hi = __builtin_amdgcn_ds_bpermute(addr, (int)pd[ks * 2 + 1][i & 1]);
          av[ks].u[i] = (unsigned)(quad >= 2 ? hi : lo);
        }

#pragma unroll
      for (int ks = 0; ks < 2; ks++) {
        bf16x8 bvv[4];
#pragma unroll
        for (int nd = 0; nd < 4; nd++) {
          const int row = nd * 16 + l15;
          const int cp = ((ks << 2) + quad) ^ (row & 7);
          bvv[nd] = *(const bf16x8*)&cV[(row << 6) + (cp << 3)];
        }
        __builtin_amdgcn_s_setprio(1);
#pragma unroll
        for (int nd = 0; nd < 4; nd++)
          acc_o[nd] = __builtin_amdgcn_mfma_f32_16x16x32_bf16(
              av[ks].v, bvv[nd], acc_o[nd], 0, 0, 0);
        __builtin_amdgcn_s_setprio(0);
      }

      par ^= 1;
    }

    const float inv = 1.0f / l_i;
#pragma unroll
    for (int r = 0; r < 4; r++) {
      const float linv = bperm_f((quad * 4 + r) << 2, inv);
      const int sRow = qbase + quad * 4 + r;
#pragma unroll
      for (int nd = 0; nd < 4; nd++) {
        const int d = nd * 16 + l15;
        ob[(((size_t)(b * S_LEN + sRow)) << 10) + h * 64 + d] =
            (bf16_t)(acc_o[nd][r] * linv);
      }
    }
  };

  stage(0, Kt0, Vt0);            // tile 0 of phase A into buffer 0
  phase(31 - pair, true);        // big tile first; prefetch B's tile 0 at seam
  phase(pair, false);            // total bodies = (32-p) + (p+1) = 33, uniform
}

// ---------------------------------------------------------------------------
extern "C" void kernel_launch(void* const* d_in, const int* in_sizes, int n_in,
                              void* d_out, int out_size, void* d_ws, size_t ws_size,
                              hipStream_t stream)
{
  (void)in_sizes; (void)n_in; (void)out_size;
  const float* Q  = (const float*)d_in[0];
  const float* K  = (const float*)d_in[1];
  const float* V  = (const float*)d_in[2];
  const float* Wq = (const float*)d_in[4];
  const float* bq = (const float*)d_in[5];
  const float* Wk = (const float*)d_in[6];
  const float* bk = (const float*)d_in[7];
  const float* Wv = (const float*)d_in[8];
  const float* bv = (const float*)d_in[9];
  const float* Wo = (const float*)d_in[10];
  const float* bo = (const float*)d_in[11];
  float* out = (float*)d_out;

  const size_t NELT = (size_t)MROWS * D_MODEL;        // 8 Mi elements
  const size_t WELT = (size_t)D_MODEL * D_MODEL;      // 1 Mi elements

  // New layout (104 MB): qp|kp|vtp (48MB) | weights (8MB) | abf (48MB).
  // obuf ALIASES abf (abf dead after qkv8; obuf born after).
  const size_t need_new = (3 * NELT + 4 * WELT + 3 * NELT) * sizeof(bf16_t);

  bf16_t* qp   = (bf16_t*)d_ws;
  bf16_t* kp   = qp + NELT;
  bf16_t* vtp  = kp + NELT;
  bf16_t* wqt  = vtp + NELT;
  bf16_t* wkt  = wqt + WELT;
  bf16_t* wvt  = wkt + WELT;
  bf16_t* wot  = wvt + WELT;
  bf16_t* abf  = wot + WELT;       // [3][8192][1024] bf16 (new path only)
  bf16_t* obuf = abf;              // alias: lives in abf's first 16MB

  dim3 blk(256);
  transpose_w_kernel<<<dim3(16, 16, 4), blk, 0, stream>>>(
      Wq, Wk, Wv, Wo, wqt, wkt, wvt, wot);

  if (ws_size >= need_new) {
    convert_a_kernel<<<dim3(MROWS * D_MODEL / (256 * 8), 3), blk, 0, stream>>>(
        Q, K, V, abf);
    qkv8_kernel<<<dim3((MROWS / 128) * (3 * D_MODEL / 256)), dim3(512), 0,
                  stream>>>(abf, wqt, bq, bk, bv, qp, kp, vtp);
  } else {
    // Fallback (72 MB, round-0 verified): obuf sits where abf would start.
    qkv_legacy_kernel<<<dim3(3 * D_MODEL / 128, MROWS / 128), blk, 0, stream>>>(
        Q, K, V, wqt, bq, bk, bv, qp, kp, vtp);
  }

  attn_kernel<<<dim3(16, BATCH * NHEAD), blk, 0, stream>>>(qp, kp, vtp, obuf);

  out_gemm_kernel<<<dim3(D_MODEL / 128, MROWS / 128), blk, 0, stream>>>(
      obuf, wot, bo, out);
}

// Round 7
// 356.794 us; speedup vs baseline: 1.1119x; 1.0128x over previous
//
#include <hip/hip_runtime.h>

typedef __bf16 bf16_t;
typedef __bf16 bf16x8 __attribute__((ext_vector_type(8)));
typedef __bf16 bf16x4 __attribute__((ext_vector_type(4)));
typedef float  floatx4 __attribute__((ext_vector_type(4)));

#define D_MODEL 1024
#define S_LEN   2048
#define NHEAD   16
#define DK      64
#define BATCH   4
#define MROWS   (BATCH * S_LEN)   // 8192
// 1/sqrt(64) * log2(e): fold into Q so scores arrive in exp2 domain
#define QSCALE  0.18033688011112042f

__device__ __forceinline__ void load_lds16(const void* gsrc, void* ldst) {
  __builtin_amdgcn_global_load_lds(
      (const __attribute__((address_space(1))) void*)gsrc,
      (__attribute__((address_space(3))) void*)ldst, 16, 0, 0);
}

__device__ __forceinline__ unsigned pack_bf16(float a, float b) {
  union { bf16_t h[2]; unsigned u; } t;
  t.h[0] = (bf16_t)a; t.h[1] = (bf16_t)b;
  return t.u;
}

__device__ __forceinline__ float bperm_f(int addr, float v) {
  union { float f; int i; } in, out;
  in.f = v;
  out.i = __builtin_amdgcn_ds_bpermute(addr, in.i);
  return out.f;
}

__device__ __forceinline__ void barrier_mem() {
  asm volatile("" ::: "memory");
  __builtin_amdgcn_s_barrier();
  asm volatile("" ::: "memory");
}

// ---------------------------------------------------------------------------
// fp32 -> bf16 convert of the three activation inputs into one [3][8192][1024]
// contiguous bf16 buffer (A operand of the 8-phase QKV GEMM).
// ---------------------------------------------------------------------------
__global__ __launch_bounds__(256)
void convert_a_kernel(const float* __restrict__ Q, const float* __restrict__ K,
                      const float* __restrict__ V, bf16_t* __restrict__ Abf)
{
  const int z = blockIdx.y;
  const float* src = z == 0 ? Q : (z == 1 ? K : V);
  bf16_t* dst = Abf + ((size_t)z << 23);          // z * 8192 * 1024
  const size_t off = ((size_t)blockIdx.x * 256 + threadIdx.x) * 8;
  floatx4 a = *(const floatx4*)&src[off];
  floatx4 b = *(const floatx4*)&src[off + 4];
  bf16x8 o;
  o[0] = (bf16_t)a[0]; o[1] = (bf16_t)a[1];
  o[2] = (bf16_t)a[2]; o[3] = (bf16_t)a[3];
  o[4] = (bf16_t)b[0]; o[5] = (bf16_t)b[1];
  o[6] = (bf16_t)b[2]; o[7] = (bf16_t)b[3];
  *(bf16x8*)&dst[off] = o;
}

// ---------------------------------------------------------------------------
// Fused weight transpose + fp32->bf16 for all 4 weights (z selects).
// wqt/wkt/wvt are contiguous -> form a [3072][1024] matrix for the QKV GEMM.
// ---------------------------------------------------------------------------
__global__ __launch_bounds__(256)
void transpose_w_kernel(const float* __restrict__ W0, const float* __restrict__ W1,
                        const float* __restrict__ W2, const float* __restrict__ W3,
                        bf16_t* __restrict__ T0, bf16_t* __restrict__ T1,
                        bf16_t* __restrict__ T2, bf16_t* __restrict__ T3)
{
  const int z = blockIdx.z;
  const float* W = z == 0 ? W0 : (z == 1 ? W1 : (z == 2 ? W2 : W3));
  bf16_t* Wt     = z == 0 ? T0 : (z == 1 ? T1 : (z == 2 ? T2 : T3));

  __shared__ float tile[64][65];
  const int x0 = blockIdx.x * 64;         // n
  const int y0 = blockIdx.y * 64;         // k
  const int tid = threadIdx.x;
  const int r = tid >> 4;
  const int c = (tid & 15) << 2;
#pragma unroll
  for (int p = 0; p < 4; p++) {
    floatx4 v = *(const floatx4*)&W[(size_t)(y0 + p * 16 + r) * D_MODEL + x0 + c];
    tile[p * 16 + r][c + 0] = v[0];
    tile[p * 16 + r][c + 1] = v[1];
    tile[p * 16 + r][c + 2] = v[2];
    tile[p * 16 + r][c + 3] = v[3];
  }
  __syncthreads();
#pragma unroll
  for (int p = 0; p < 4; p++) {
    int row = p * 16 + r;
    bf16x4 o;
    o[0] = (bf16_t)tile[c + 0][row];
    o[1] = (bf16_t)tile[c + 1][row];
    o[2] = (bf16_t)tile[c + 2][row];
    o[3] = (bf16_t)tile[c + 3][row];
    *(bf16x4*)&Wt[(size_t)(x0 + row) * D_MODEL + y0 + c] = o;
  }
}

// ---------------------------------------------------------------------------
// QKV projection, BM=128 x BN=256 8-phase GEMM (T2+T3+T4+T5), READ-ONCE
// buffer windows for maximal stage distance (round-7 rework):
//   M=8192, N=3072, K=1024, BK=64. Grid 768 = 3.0 rounds over 256 CUs.
//   512 threads = 8 waves (2M x 4N); wave tile 64x64 = acc[4][4].
//   LDS 96 KiB: lds[2][3][128*64] = [buf][A,B0,B1]; XOR swizzle c^(row&7)
//   on BOTH gll source chunk and ds_read (involution; verified pair).
//   KEY CHANGE vs round 6: ALL fragments of a buffer are read in ONE phase
//   (ph0 for buf0, ph4 for buf1; 16 ds_read_b128 -> Af[4][2],Bf[4][2]),
//   so every half is dead after that phase. Stage slots then sit at
//   ph1-3 / ph5-7 with forced-landing distances of 4-6 phases:
//     it: ph0 read buf0(t=2it), MFMA q00 | ph1 st buf0.B0(2it+2), q01
//         ph2 st buf0.B1, q11 | ph3 st buf0.A, q10, vmcnt(6)   <- forces
//             buf1's tile (staged prev ph5-7, dist 4-6ph) before ph4
//         ph4 read buf1(2it+1), q00 | ph5-7 st buf1.{B0,B1,A}(2it+3),
//             q01,q11,q10, vmcnt(6) at ph7 <- forces buf0's next tile.
//   vmcnt(6) keeps 6 loads (3 halves) permanently in flight; never drains.
//   LAST ITERATION PEELED (tiles 14,15 computed with NO staging; vmcnt(0)
//   at tail-ph3) -> kills the round-6 tail-wrap re-fetch (~74 MB logical).
// ---------------------------------------------------------------------------
__global__ __launch_bounds__(512, 2)
void qkv8_kernel(const bf16_t* __restrict__ Abf, const bf16_t* __restrict__ Wcat,
                 const float* __restrict__ bq, const float* __restrict__ bk,
                 const float* __restrict__ bv,
                 bf16_t* __restrict__ qo, bf16_t* __restrict__ ko,
                 bf16_t* __restrict__ vo)
{
  __shared__ bf16_t lds[2][3][128 * 64];   // 98304 B

  // Bijective XCD swizzle: 768 blocks, 8 XCDs x 96 (bn-major within XCD:
  // the 12 bn-blocks sharing one A panel are consecutive -> L2-shared).
  const int orig = blockIdx.x;                 // 0..767
  const int L = (orig & 7) * 96 + (orig >> 3);
  const int bm = L / 12, bn = L % 12;          // bm 0..63, bn 0..11
  const int m0 = bm << 7;                      // BM=128
  const int n0 = bn << 8;                      // BN=256
  const int z  = n0 >> 10;                     // projection (block-uniform)
  const bf16_t* A = Abf + ((size_t)z << 23);

  const int tid = threadIdx.x;
  const int wid = tid >> 6, lane = tid & 63;
  const int l15 = lane & 15, quad = lane >> 4;
  const int wm = wid >> 2, wn = wid & 3;

  floatx4 acc[4][4] = {};
  bf16x8 Af[4][2], Bf[4][2];

  // half id: 0=A (rows m0..m0+127), 1=B0 (n0..n0+127), 2=B1 (n0+128..+255)
  auto stage_half = [&](int buf, int half, int kt) {
    const bf16_t* src = half == 0
        ? (A + (size_t)m0 * D_MODEL)
        : (Wcat + (size_t)(n0 + ((half - 1) << 7)) * D_MODEL);
    const int k0 = kt << 6;
    bf16_t* dst = &lds[buf][half][0];
#pragma unroll
    for (int p = 0; p < 2; p++) {
      const int slot = (p << 9) + tid;         // 0..1023
      const int row = slot >> 3;               // 0..127
      const int c = (slot & 7) ^ (row & 7);    // pre-swizzled source chunk
      load_lds16(&src[(size_t)row * D_MODEL + k0 + (c << 3)],
                 &dst[(size_t)((p << 9) + (wid << 6)) << 3]);
    }
  };

  // VMW: 0=none, 1=vmcnt(6), 2=vmcnt(0)
#define PHASE(BUF, MH, NH, DORD, DOST, SBUF, SHALF, SKT, VMW)                  \
  {                                                                            \
    if (DORD) {                                                                \
      _Pragma("unroll") for (int mi = 0; mi < 4; mi++) {                       \
        const int row = (wm << 6) + (mi << 4) + l15;                           \
        _Pragma("unroll") for (int ks = 0; ks < 2; ks++) {                     \
          const int ck = (ks << 2) + quad;                                     \
          Af[mi][ks] = *(const bf16x8*)&lds[BUF][0]                            \
              [(row << 6) + ((ck ^ (row & 7)) << 3)];                          \
        }                                                                      \
      }                                                                        \
      _Pragma("unroll") for (int ni = 0; ni < 4; ni++) {                       \
        const int row = ((wn & 1) << 6) + (ni << 4) + l15;                     \
        _Pragma("unroll") for (int ks = 0; ks < 2; ks++) {                     \
          const int ck = (ks << 2) + quad;                                     \
          Bf[ni][ks] = *(const bf16x8*)&lds[BUF][1 + (wn >> 1)]                \
              [(row << 6) + ((ck ^ (row & 7)) << 3)];                          \
        }                                                                      \
      }                                                                        \
    }                                                                          \
    if (DOST) stage_half(SBUF, SHALF, SKT);                                    \
    barrier_mem();                                                             \
    __builtin_amdgcn_s_setprio(1);                                             \
    _Pragma("unroll") for (int mi = 0; mi < 2; mi++)                           \
      _Pragma("unroll") for (int ni = 0; ni < 2; ni++)                         \
        _Pragma("unroll") for (int ks = 0; ks < 2; ks++)                       \
          acc[(MH) * 2 + mi][(NH) * 2 + ni] =                                  \
              __builtin_amdgcn_mfma_f32_16x16x32_bf16(                         \
                  Af[(MH) * 2 + mi][ks], Bf[(NH) * 2 + ni][ks],                \
                  acc[(MH) * 2 + mi][(NH) * 2 + ni], 0, 0, 0);                 \
    __builtin_amdgcn_s_setprio(0);                                             \
    if ((VMW) == 1) asm volatile("s_waitcnt vmcnt(6)" ::: "memory");           \
    if ((VMW) == 2) asm volatile("s_waitcnt vmcnt(0)" ::: "memory");           \
    barrier_mem();                                                             \
  }

  // Prologue: buf0 <- tile0 (6 loads), buf1 <- tile1 (6 loads);
  // vmcnt(6) forces tile0 landed, tile1 stays in flight.
  stage_half(0, 1, 0);
  stage_half(0, 2, 0);
  stage_half(0, 0, 0);
  stage_half(1, 1, 1);
  stage_half(1, 2, 1);
  stage_half(1, 0, 1);
  asm volatile("s_waitcnt vmcnt(6)" ::: "memory");
  barrier_mem();

  for (int it = 0; it < 7; it++) {
    const int tu2 = 2 * it + 2;          // next buf0 tile (<=14)
    const int tv2 = 2 * it + 3;          // next buf1 tile (<=15)
    PHASE(0, 0, 0, 1, 0, 0, 0, 0,   0)   // read buf0 all; q00
    PHASE(0, 0, 1, 0, 1, 0, 1, tu2, 0)   // stage buf0.B0(u+2); q01
    PHASE(0, 1, 1, 0, 1, 0, 2, tu2, 0)   // stage buf0.B1(u+2); q11
    PHASE(0, 1, 0, 0, 1, 0, 0, tu2, 1)   // stage buf0.A(u+2); q10; vmcnt(6)
    PHASE(1, 0, 0, 1, 0, 0, 0, 0,   0)   // read buf1 all; q00
    PHASE(1, 0, 1, 0, 1, 1, 1, tv2, 0)   // stage buf1.B0(v+2); q01
    PHASE(1, 1, 1, 0, 1, 1, 2, tv2, 0)   // stage buf1.B1(v+2); q11
    PHASE(1, 1, 0, 0, 1, 1, 0, tv2, 1)   // stage buf1.A(v+2); q10; vmcnt(6)
  }
  // Peeled tail: tiles 14 (buf0) and 15 (buf1), NO staging.
  PHASE(0, 0, 0, 1, 0, 0, 0, 0, 0)
  PHASE(0, 0, 1, 0, 0, 0, 0, 0, 0)
  PHASE(0, 1, 1, 0, 0, 0, 0, 0, 0)
  PHASE(0, 1, 0, 0, 0, 0, 0, 0, 2)       // vmcnt(0): tile15 landed
  PHASE(1, 0, 0, 1, 0, 0, 0, 0, 0)
  PHASE(1, 0, 1, 0, 0, 0, 0, 0, 0)
  PHASE(1, 1, 1, 0, 0, 0, 0, 0, 0)
  PHASE(1, 1, 0, 0, 0, 0, 0, 0, 0)

#undef PHASE

  const float* bias = z == 0 ? bq : (z == 1 ? bk : bv);
  bf16_t* outp      = z == 0 ? qo : (z == 1 ? ko : vo);
  const float scl   = (z == 0) ? QSCALE : 1.0f;
#pragma unroll
  for (int mi = 0; mi < 4; mi++) {
#pragma unroll
    for (int ni = 0; ni < 4; ni++) {
      const int nn = (n0 + (wn << 6) + (ni << 4) + l15) & (D_MODEL - 1);
      const float bvv = bias[nn];
      const int h = nn >> 6, d = nn & 63;
#pragma unroll
      for (int r = 0; r < 4; r++) {
        const int m = m0 + (wm << 6) + (mi << 4) + quad * 4 + r;
        const int b = m >> 11, srow = m & (S_LEN - 1);
        float v = (acc[mi][ni][r] + bvv) * scl;
        if (z < 2) {
          outp[((((size_t)(b * NHEAD + h) << 11) + srow) << 6) + d] = (bf16_t)v;
        } else {
          outp[((((size_t)(b * NHEAD + h) << 6) + d) << 11) + srow] = (bf16_t)v;
        }
      }
    }
  }
}

// ---------------------------------------------------------------------------
// LEGACY QKV (round-0 verified, 24 KB LDS, serial staging) — fallback when
// ws_size cannot hold the bf16 A buffer. Reads fp32 A directly.
// ---------------------------------------------------------------------------
__global__ __launch_bounds__(256, 3)
void qkv_legacy_kernel(const float* __restrict__ Qi, const float* __restrict__ Ki,
                       const float* __restrict__ Vi, const bf16_t* __restrict__ Wcat,
                       const float* __restrict__ bq, const float* __restrict__ bk,
                       const float* __restrict__ bv,
                       bf16_t* __restrict__ qo, bf16_t* __restrict__ ko,
                       bf16_t* __restrict__ vo)
{
  __shared__ float  Asf[128 * 32];
  __shared__ bf16_t Bs[128 * 32];

  const int L = blockIdx.x + 24 * blockIdx.y;
  const int j = (L >> 3) & 7;
  const int s = ((L >> 6) << 3) | (L & 7);
  const int z = s >> 6;
  const int n0g = (((z << 3) | j)) << 7;
  const int m0 = (s & 63) << 7;

  const float* A = z == 0 ? Qi : (z == 1 ? Ki : Vi);

  const int tid = threadIdx.x;
  const int lane = tid & 63;
  const int w = tid >> 6;
  const int l15 = lane & 15;
  const int quad = lane >> 4;
  const int wy = (w >> 1) << 6;
  const int wx = (w & 1) << 6;
  const int w64 = w << 6;

  floatx4 acc[4][4];
#pragma unroll
  for (int i = 0; i < 4; i++)
#pragma unroll
    for (int jj = 0; jj < 4; jj++)
#pragma unroll
      for (int r = 0; r < 4; r++) acc[i][jj][r] = 0.0f;

  for (int kt = 0; kt < 32; kt++) {
    const int k0 = kt << 5;
    __syncthreads();
#pragma unroll
    for (int p = 0; p < 2; p++) {
      int slot = p * 256 + w64 + lane;
      int row = slot >> 2;
      int kc = (slot & 3) ^ (row & 3);
      load_lds16(&Wcat[(size_t)(n0g + row) * D_MODEL + k0 + (kc << 3)],
                 &Bs[(size_t)(p * 256 + w64) << 3]);
    }
#pragma unroll
    for (int p = 0; p < 4; p++) {
      int sbase = (w << 8) + (p << 6);
      int slot = sbase + lane;
      int row = slot >> 3;
      int ca = (slot & 7) ^ (row & 7);
      load_lds16(&A[(size_t)(m0 + row) * D_MODEL + k0 + (ca << 2)],
                 &Asf[(size_t)sbase << 2]);
    }
    __syncthreads();

    bf16x8 af[4], bfv[4];
#pragma unroll
    for (int mi = 0; mi < 4; mi++) {
      const int m = wy + mi * 16 + l15;
      const int e = m & 7;
      floatx4 f0 = *(const floatx4*)&Asf[(m << 5) + ((((quad << 1))     ^ e) << 2)];
      floatx4 f1 = *(const floatx4*)&Asf[(m << 5) + ((((quad << 1) | 1) ^ e) << 2)];
      bf16x8 o;
      o[0] = (bf16_t)f0[0]; o[1] = (bf16_t)f0[1];
      o[2] = (bf16_t)f0[2]; o[3] = (bf16_t)f0[3];
      o[4] = (bf16_t)f1[0]; o[5] = (bf16_t)f1[1];
      o[6] = (bf16_t)f1[2]; o[7] = (bf16_t)f1[3];
      af[mi] = o;
    }
#pragma unroll
    for (int ni = 0; ni < 4; ni++) {
      int n = wx + ni * 16 + l15;
      bfv[ni] = *(const bf16x8*)&Bs[n * 32 + ((quad ^ (n & 3)) << 3)];
    }
#pragma unroll
    for (int mi = 0; mi < 4; mi++)
#pragma unroll
      for (int ni = 0; ni < 4; ni++)
        acc[mi][ni] = __builtin_amdgcn_mfma_f32_16x16x32_bf16(
            af[mi], bfv[ni], acc[mi][ni], 0, 0, 0);
  }

  const float* bias = z == 0 ? bq : (z == 1 ? bk : bv);
  bf16_t* outp      = z == 0 ? qo : (z == 1 ? ko : vo);
  const float scl   = (z == 0) ? QSCALE : 1.0f;
#pragma unroll
  for (int mi = 0; mi < 4; mi++) {
#pragma unroll
    for (int ni = 0; ni < 4; ni++) {
      const int nn = (n0g + wx + ni * 16 + l15) & (D_MODEL - 1);
      const float bvv = bias[nn];
      const int h = nn >> 6, d = nn & 63;
#pragma unroll
      for (int r = 0; r < 4; r++) {
        const int m = m0 + wy + mi * 16 + quad * 4 + r;
        const int b = m >> 11, srow = m & (S_LEN - 1);
        float v = (acc[mi][ni][r] + bvv) * scl;
        if (z < 2) {
          outp[((((size_t)(b * NHEAD + h) << 11) + srow) << 6) + d] = (bf16_t)v;
        } else {
          outp[((((size_t)(b * NHEAD + h) << 6) + d) << 11) + srow] = (bf16_t)v;
        }
      }
    }
  }
}

// ---------------------------------------------------------------------------
// Output GEMM: out = obuf(bf16) @ Wo + bo, fp32 out. Dual global_load_lds.
// (round-0 proven serial form; grid 512 = 2.0 exact rounds)
// ---------------------------------------------------------------------------
__global__ __launch_bounds__(256)
void out_gemm_kernel(const bf16_t* __restrict__ A, const bf16_t* __restrict__ Wt,
                     const float* __restrict__ bias, float* __restrict__ out)
{
  __shared__ bf16_t As[128 * 32];
  __shared__ bf16_t Bs[128 * 32];
  const int L = blockIdx.x + 8 * blockIdx.y;      // 0..511
  const int n0 = (((L >> 3) & 7)) << 7;
  const int m0 = ((((L >> 6) << 3) | (L & 7))) << 7;
  const int tid = threadIdx.x;
  const int lane = tid & 63;
  const int w = tid >> 6;
  const int l15 = lane & 15;
  const int quad = lane >> 4;
  const int wy = (w >> 1) << 6;
  const int wx = (w & 1) << 6;
  const int w64 = w << 6;

  floatx4 acc[4][4];
#pragma unroll
  for (int i = 0; i < 4; i++)
#pragma unroll
    for (int jj = 0; jj < 4; jj++)
#pragma unroll
      for (int r = 0; r < 4; r++) acc[i][jj][r] = 0.0f;

  for (int kt = 0; kt < 32; kt++) {
    const int k0 = kt << 5;
    __syncthreads();
#pragma unroll
    for (int p = 0; p < 2; p++) {
      int slot = p * 256 + w64 + lane;
      int row = slot >> 2;
      int kc = (slot & 3) ^ (row & 3);
      load_lds16(&A[(size_t)(m0 + row) * D_MODEL + k0 + (kc << 3)],
                 &As[(size_t)(p * 256 + w64) << 3]);
      load_lds16(&Wt[(size_t)(n0 + row) * D_MODEL + k0 + (kc << 3)],
                 &Bs[(size_t)(p * 256 + w64) << 3]);
    }
    __syncthreads();

    bf16x8 af[4], bfv[4];
#pragma unroll
    for (int mi = 0; mi < 4; mi++) {
      int m = wy + mi * 16 + l15;
      af[mi] = *(const bf16x8*)&As[m * 32 + ((quad ^ (m & 3)) << 3)];
    }
#pragma unroll
    for (int ni = 0; ni < 4; ni++) {
      int n = wx + ni * 16 + l15;
      bfv[ni] = *(const bf16x8*)&Bs[n * 32 + ((quad ^ (n & 3)) << 3)];
    }
#pragma unroll
    for (int mi = 0; mi < 4; mi++)
#pragma unroll
      for (int ni = 0; ni < 4; ni++)
        acc[mi][ni] = __builtin_amdgcn_mfma_f32_16x16x32_bf16(
            af[mi], bfv[ni], acc[mi][ni], 0, 0, 0);
  }

#pragma unroll
  for (int mi = 0; mi < 4; mi++) {
#pragma unroll
    for (int ni = 0; ni < 4; ni++) {
      const int nbase = n0 + wx + ni * 16 + l15;
      const float bv = bias[nbase];
#pragma unroll
      for (int r = 0; r < 4; r++) {
        const int m = m0 + wy + mi * 16 + quad * 4 + r;
        out[((size_t)m << 10) + nbase] = acc[mi][ni][r] + bv;
      }
    }
  }
}

// ---------------------------------------------------------------------------
// Causal flash attention, S^T formulation, BALANCED pairing (r5-verified).
// XCD-clustering remap + setprio + defer-max (round-4 verified).
// ---------------------------------------------------------------------------
__global__ __launch_bounds__(256, 4)
void attn_kernel(const bf16_t* __restrict__ qp, const bf16_t* __restrict__ kp,
                 const bf16_t* __restrict__ vtp, bf16_t* __restrict__ ob)
{
  __shared__ bf16_t Kt0[64 * 64];
  __shared__ bf16_t Kt1[64 * 64];
  __shared__ bf16_t Vt0[64 * 64];
  __shared__ bf16_t Vt1[64 * 64];

  const int lin = blockIdx.x + (blockIdx.y << 4);   // 0..1023
  const int pair = (lin >> 3) & 15;                 // 0..15
  const int bh = (lin & 7) | ((lin >> 7) << 3);     // 0..63
  const int tid = threadIdx.x;
  const int w = tid >> 6;
  const int lane = tid & 63;
  const int l15 = lane & 15;
  const int quad = lane >> 4;

  const bf16_t* Qh = qp + ((size_t)bh << 17);
  const bf16_t* Kh = kp + ((size_t)bh << 17);
  const bf16_t* Vh = vtp + ((size_t)bh << 17);   // [64][2048]
  const int b = bh >> 4, h = bh & 15;

  auto stage = [&](int k0s, bf16_t* dK, bf16_t* dV) {
#pragma unroll
    for (int p = 0; p < 2; p++) {
      const int sbase = (w << 7) + (p << 6);
      const int slot = sbase + lane;
      const int row = slot >> 3;
      const int c = (slot & 7) ^ (row & 7);
      load_lds16(&Kh[((size_t)(k0s + row) << 6) + (c << 3)], &dK[sbase << 3]);
      load_lds16(&Vh[((size_t)row << 11) + k0s + (c << 3)], &dV[sbase << 3]);
    }
  };

  int par = 0;   // global tile-counter parity: current buffer index

  auto phase = [&](int qt, bool prefetch_next_phase) {
    const int q0 = qt << 6;
    const int qbase = q0 + (w << 4);       // wave's 16 q-rows
    const int nkb = qt + 1;

    bf16x8 qf[2];
#pragma unroll
    for (int ks = 0; ks < 2; ks++)
      qf[ks] = *(const bf16x8*)&Qh[(size_t)(qbase + l15) * DK +
                                   ks * 32 + (quad << 3)];

    floatx4 acc_o[4];
    float m_i = -1e30f, l_i = 0.0f;
#pragma unroll
    for (int nd = 0; nd < 4; nd++)
#pragma unroll
      for (int r = 0; r < 4; r++) acc_o[nd][r] = 0.0f;

    for (int kb = 0; kb < nkb; kb++) {
      const int k0 = kb << 6;
      __syncthreads();   // drains this tile's gll (issued one body ago)

      const bf16_t* cK = par ? Kt1 : Kt0;
      const bf16_t* cV = par ? Vt1 : Vt0;
      bf16_t* nK = par ? Kt0 : Kt1;
      bf16_t* nV = par ? Vt0 : Vt1;

      if (kb + 1 < nkb)             stage((kb + 1) << 6, nK, nV);
      else if (prefetch_next_phase) stage(0, nK, nV);

      bf16x8 bk[2][4];
#pragma unroll
      for (int ks = 0; ks < 2; ks++)
#pragma unroll
        for (int ni = 0; ni < 4; ni++) {
          const int row = ni * 16 + l15;
          const int cp = ((ks << 2) + quad) ^ (row & 7);
          bk[ks][ni] = *(const bf16x8*)&cK[(row << 6) + (cp << 3)];
        }

      floatx4 st[4];
#pragma unroll
      for (int ni = 0; ni < 4; ni++)
#pragma unroll
        for (int r = 0; r < 4; r++) st[ni][r] = 0.0f;
      __builtin_amdgcn_s_setprio(1);
#pragma unroll
      for (int ks = 0; ks < 2; ks++)
#pragma unroll
        for (int ni = 0; ni < 4; ni++)
          st[ni] = __builtin_amdgcn_mfma_f32_16x16x32_bf16(
              bk[ks][ni], qf[ks], st[ni], 0, 0, 0);
      __builtin_amdgcn_s_setprio(0);

      if (k0 + 63 > qbase) {
        const int qrow = qbase + l15;
#pragma unroll
        for (int ni = 0; ni < 4; ni++) {
          const int keyb = k0 + ni * 16 + quad * 4;
#pragma unroll
          for (int r = 0; r < 4; r++)
            if (keyb + r > qrow) st[ni][r] = -1e30f;
        }
      }

      float v = st[0][0];
#pragma unroll
      for (int ni = 0; ni < 4; ni++)
#pragma unroll
        for (int r = 0; r < 4; r++) v = fmaxf(v, st[ni][r]);
      v = fmaxf(v, __shfl_xor(v, 16));
      v = fmaxf(v, __shfl_xor(v, 32));

      // Defer-max (T13): skip rescale when tile max doesn't grow past THR.
      if (!__all(v <= m_i + 5.0f)) {
        const float mn = fmaxf(m_i, v);
        const float alpha = __builtin_amdgcn_exp2f(m_i - mn);
        m_i = mn;
        l_i *= alpha;
#pragma unroll
        for (int r = 0; r < 4; r++) {
          float ab = bperm_f((quad * 4 + r) << 2, alpha);
#pragma unroll
          for (int nd = 0; nd < 4; nd++) acc_o[nd][r] *= ab;
        }
      }

      unsigned pd[4][2];
      float ssum = 0.0f;
#pragma unroll
      for (int c = 0; c < 4; c++)
#pragma unroll
        for (int hh = 0; hh < 2; hh++) {
          float p0 = __builtin_amdgcn_exp2f(st[c][2 * hh]     - m_i);
          float p1 = __builtin_amdgcn_exp2f(st[c][2 * hh + 1] - m_i);
          ssum += p0 + p1;
          pd[c][hh] = pack_bf16(p0, p1);
        }
      ssum += __shfl_xor(ssum, 16);
      ssum += __shfl_xor(ssum, 32);
      l_i += ssum;

      union AV { unsigned u[4]; bf16x8 v; };
      AV av[2];
#pragma unroll
      for (int ks = 0; ks < 2; ks++)
#pragma unroll
        for (int i = 0; i < 4; i++) {
          const int addr = ((((2 * quad + (i >> 1)) & 3) << 4) | l15) << 2;
          int lo = __builtin_amdgcn_ds_bpermute(addr, (int)pd[ks * 2][i & 1]);
          int hi = __builtin_amdgcn_ds_bpermute(addr, (int)pd[ks * 2 + 1][i & 1]);
          av[ks].u[i] = (unsigned)(quad >= 2 ? hi : lo);
        }

#pragma unroll
      for (int ks = 0; ks < 2; ks++) {
        bf16x8 bvv[4];
#pragma unroll
        for (int nd = 0; nd < 4; nd++) {
          const int row = nd * 16 + l15;
          const int cp = ((ks << 2) + quad) ^ (row & 7);
          bvv[nd] = *(const bf16x8*)&cV[(row << 6) + (cp << 3)];
        }
        __builtin_amdgcn_s_setprio(1);
#pragma unroll
        for (int nd = 0; nd < 4; nd++)
          acc_o[nd] = __builtin_amdgcn_mfma_f32_16x16x32_bf16(
              av[ks].v, bvv[nd], acc_o[nd], 0, 0, 0);
        __builtin_amdgcn_s_setprio(0);
      }

      par ^= 1;
    }

    const float inv = 1.0f / l_i;
#pragma unroll
    for (int r = 0; r < 4; r++) {
      const float linv = bperm_f((quad * 4 + r) << 2, inv);
      const int sRow = qbase + quad * 4 + r;
#pragma unroll
      for (int nd = 0; nd < 4; nd++) {
        const int d = nd * 16 + l15;
        ob[(((size_t)(b * S_LEN + sRow)) << 10) + h * 64 + d] =
            (bf16_t)(acc_o[nd][r] * linv);
      }
    }
  };

  stage(0, Kt0, Vt0);            // tile 0 of phase A into buffer 0
  phase(31 - pair, true);        // big tile first; prefetch B's tile 0 at seam
  phase(pair, false);            // total bodies = (32-p) + (p+1) = 33, uniform
}

// ---------------------------------------------------------------------------
extern "C" void kernel_launch(void* const* d_in, const int* in_sizes, int n_in,
                              void* d_out, int out_size, void* d_ws, size_t ws_size,
                              hipStream_t stream)
{
  (void)in_sizes; (void)n_in; (void)out_size;
  const float* Q  = (const float*)d_in[0];
  const float* K  = (const float*)d_in[1];
  const float* V  = (const float*)d_in[2];
  const float* Wq = (const float*)d_in[4];
  const float* bq = (const float*)d_in[5];
  const float* Wk = (const float*)d_in[6];
  const float* bk = (const float*)d_in[7];
  const float* Wv = (const float*)d_in[8];
  const float* bv = (const float*)d_in[9];
  const float* Wo = (const float*)d_in[10];
  const float* bo = (const float*)d_in[11];
  float* out = (float*)d_out;

  const size_t NELT = (size_t)MROWS * D_MODEL;        // 8 Mi elements
  const size_t WELT = (size_t)D_MODEL * D_MODEL;      // 1 Mi elements

  // New layout (104 MB): qp|kp|vtp (48MB) | weights (8MB) | abf (48MB).
  // obuf ALIASES abf (abf dead after qkv8; obuf born after).
  const size_t need_new = (3 * NELT + 4 * WELT + 3 * NELT) * sizeof(bf16_t);

  bf16_t* qp   = (bf16_t*)d_ws;
  bf16_t* kp   = qp + NELT;
  bf16_t* vtp  = kp + NELT;
  bf16_t* wqt  = vtp + NELT;
  bf16_t* wkt  = wqt + WELT;
  bf16_t* wvt  = wkt + WELT;
  bf16_t* wot  = wvt + WELT;
  bf16_t* abf  = wot + WELT;       // [3][8192][1024] bf16 (new path only)
  bf16_t* obuf = abf;              // alias: lives in abf's first 16MB

  dim3 blk(256);
  transpose_w_kernel<<<dim3(16, 16, 4), blk, 0, stream>>>(
      Wq, Wk, Wv, Wo, wqt, wkt, wvt, wot);

  if (ws_size >= need_new) {
    convert_a_kernel<<<dim3(MROWS * D_MODEL / (256 * 8), 3), blk, 0, stream>>>(
        Q, K, V, abf);
    qkv8_kernel<<<dim3((MROWS / 128) * (3 * D_MODEL / 256)), dim3(512), 0,
                  stream>>>(abf, wqt, bq, bk, bv, qp, kp, vtp);
  } else {
    // Fallback (72 MB, round-0 verified): obuf sits where abf would start.
    qkv_legacy_kernel<<<dim3(3 * D_MODEL / 128, MROWS / 128), blk, 0, stream>>>(
        Q, K, V, wqt, bq, bk, bv, qp, kp, vtp);
  }

  attn_kernel<<<dim3(16, BATCH * NHEAD), blk, 0, stream>>>(qp, kp, vtp, obuf);

  out_gemm_kernel<<<dim3(D_MODEL / 128, MROWS / 128), blk, 0, stream>>>(
      obuf, wot, bo, out);
}

// Round 8
// 352.209 us; speedup vs baseline: 1.1263x; 1.0130x over previous
//
#include <hip/hip_runtime.h>

typedef __bf16 bf16_t;
typedef __bf16 bf16x8 __attribute__((ext_vector_type(8)));
typedef __bf16 bf16x4 __attribute__((ext_vector_type(4)));
typedef float  floatx4 __attribute__((ext_vector_type(4)));

#define D_MODEL 1024
#define S_LEN   2048
#define NHEAD   16
#define DK      64
#define BATCH   4
#define MROWS   (BATCH * S_LEN)   // 8192
// 1/sqrt(64) * log2(e): fold into Q so scores arrive in exp2 domain
#define QSCALE  0.18033688011112042f

__device__ __forceinline__ void load_lds16(const void* gsrc, void* ldst) {
  __builtin_amdgcn_global_load_lds(
      (const __attribute__((address_space(1))) void*)gsrc,
      (__attribute__((address_space(3))) void*)ldst, 16, 0, 0);
}

__device__ __forceinline__ unsigned pack_bf16(float a, float b) {
  union { bf16_t h[2]; unsigned u; } t;
  t.h[0] = (bf16_t)a; t.h[1] = (bf16_t)b;
  return t.u;
}

__device__ __forceinline__ float bperm_f(int addr, float v) {
  union { float f; int i; } in, out;
  in.f = v;
  out.i = __builtin_amdgcn_ds_bpermute(addr, in.i);
  return out.f;
}

// ---------------------------------------------------------------------------
// fp32 -> bf16 convert of the three activation inputs into one [3][8192][1024]
// contiguous bf16 buffer (A operand of the bf16 QKV GEMM).
// ---------------------------------------------------------------------------
__global__ __launch_bounds__(256)
void convert_a_kernel(const float* __restrict__ Q, const float* __restrict__ K,
                      const float* __restrict__ V, bf16_t* __restrict__ Abf)
{
  const int z = blockIdx.y;
  const float* src = z == 0 ? Q : (z == 1 ? K : V);
  bf16_t* dst = Abf + ((size_t)z << 23);          // z * 8192 * 1024
  const size_t off = ((size_t)blockIdx.x * 256 + threadIdx.x) * 8;
  floatx4 a = *(const floatx4*)&src[off];
  floatx4 b = *(const floatx4*)&src[off + 4];
  bf16x8 o;
  o[0] = (bf16_t)a[0]; o[1] = (bf16_t)a[1];
  o[2] = (bf16_t)a[2]; o[3] = (bf16_t)a[3];
  o[4] = (bf16_t)b[0]; o[5] = (bf16_t)b[1];
  o[6] = (bf16_t)b[2]; o[7] = (bf16_t)b[3];
  *(bf16x8*)&dst[off] = o;
}

// ---------------------------------------------------------------------------
// Fused weight transpose + fp32->bf16 for all 4 weights (z selects).
// wqt/wkt/wvt are contiguous -> form a [3072][1024] matrix for the QKV GEMM.
// ---------------------------------------------------------------------------
__global__ __launch_bounds__(256)
void transpose_w_kernel(const float* __restrict__ W0, const float* __restrict__ W1,
                        const float* __restrict__ W2, const float* __restrict__ W3,
                        bf16_t* __restrict__ T0, bf16_t* __restrict__ T1,
                        bf16_t* __restrict__ T2, bf16_t* __restrict__ T3)
{
  const int z = blockIdx.z;
  const float* W = z == 0 ? W0 : (z == 1 ? W1 : (z == 2 ? W2 : W3));
  bf16_t* Wt     = z == 0 ? T0 : (z == 1 ? T1 : (z == 2 ? T2 : T3));

  __shared__ float tile[64][65];
  const int x0 = blockIdx.x * 64;         // n
  const int y0 = blockIdx.y * 64;         // k
  const int tid = threadIdx.x;
  const int r = tid >> 4;
  const int c = (tid & 15) << 2;
#pragma unroll
  for (int p = 0; p < 4; p++) {
    floatx4 v = *(const floatx4*)&W[(size_t)(y0 + p * 16 + r) * D_MODEL + x0 + c];
    tile[p * 16 + r][c + 0] = v[0];
    tile[p * 16 + r][c + 1] = v[1];
    tile[p * 16 + r][c + 2] = v[2];
    tile[p * 16 + r][c + 3] = v[3];
  }
  __syncthreads();
#pragma unroll
  for (int p = 0; p < 4; p++) {
    int row = p * 16 + r;
    bf16x4 o;
    o[0] = (bf16_t)tile[c + 0][row];
    o[1] = (bf16_t)tile[c + 1][row];
    o[2] = (bf16_t)tile[c + 2][row];
    o[3] = (bf16_t)tile[c + 3][row];
    *(bf16x4*)&Wt[(size_t)(x0 + row) * D_MODEL + y0 + c] = o;
  }
}

// ---------------------------------------------------------------------------
// QKV projection, m97-structure (round-8): 128x128 tile, BK=32, 16 KB LDS,
// simple 2-barrier serial loop, dual global_load_lds 16B, ALL-bf16 fragments.
// Rationale: 3 rounds of 8-phase scheduling surgery moved nothing (92.8->91.5
// us, MfmaUtil ~22%); the m97 structure is measured at 912 TF on this chip
// and hides latency via ~6 blocks/CU implicit wave overlap (m114) instead of
// hand-scheduled vmcnt. Main loop lifted verbatim from out_gemm (in-harness
// verified); XCD decode + epilogue lifted verbatim from qkv_legacy.
// Only delta vs legacy: A is pre-converted bf16 (abf) -> A staging is 2x16B
// gll (not 4 fp32) and fragments read directly (no per-fragment cvt VALU).
// ---------------------------------------------------------------------------
__global__ __launch_bounds__(256)
void qkv_bf16_kernel(const bf16_t* __restrict__ Abf, const bf16_t* __restrict__ Wcat,
                     const float* __restrict__ bq, const float* __restrict__ bk,
                     const float* __restrict__ bv,
                     bf16_t* __restrict__ qo, bf16_t* __restrict__ ko,
                     bf16_t* __restrict__ vo)
{
  __shared__ bf16_t As[128 * 32];
  __shared__ bf16_t Bs[128 * 32];

  // XCD-locality decode (legacy-verified): the 8 blocks sharing one (z,y)
  // A-stripe land on one XCD (L % 8 == s % 8).
  const int L = blockIdx.x + 24 * blockIdx.y;     // 0..1535
  const int j = (L >> 3) & 7;
  const int s = ((L >> 6) << 3) | (L & 7);        // stripe 0..191
  const int z = s >> 6;                           // projection
  const int n0g = (((z << 3) | j)) << 7;          // global n over 3072
  const int m0 = (s & 63) << 7;

  const bf16_t* A = Abf + ((size_t)z << 23);

  const int tid = threadIdx.x;
  const int lane = tid & 63;
  const int w = tid >> 6;
  const int l15 = lane & 15;
  const int quad = lane >> 4;
  const int wy = (w >> 1) << 6;
  const int wx = (w & 1) << 6;
  const int w64 = w << 6;

  floatx4 acc[4][4];
#pragma unroll
  for (int i = 0; i < 4; i++)
#pragma unroll
    for (int jj = 0; jj < 4; jj++)
#pragma unroll
      for (int r = 0; r < 4; r++) acc[i][jj][r] = 0.0f;

  for (int kt = 0; kt < 32; kt++) {
    const int k0 = kt << 5;
    __syncthreads();
#pragma unroll
    for (int p = 0; p < 2; p++) {
      int slot = p * 256 + w64 + lane;
      int row = slot >> 2;
      int kc = (slot & 3) ^ (row & 3);
      load_lds16(&A[(size_t)(m0 + row) * D_MODEL + k0 + (kc << 3)],
                 &As[(size_t)(p * 256 + w64) << 3]);
      load_lds16(&Wcat[(size_t)(n0g + row) * D_MODEL + k0 + (kc << 3)],
                 &Bs[(size_t)(p * 256 + w64) << 3]);
    }
    __syncthreads();

    bf16x8 af[4], bfv[4];
#pragma unroll
    for (int mi = 0; mi < 4; mi++) {
      int m = wy + mi * 16 + l15;
      af[mi] = *(const bf16x8*)&As[m * 32 + ((quad ^ (m & 3)) << 3)];
    }
#pragma unroll
    for (int ni = 0; ni < 4; ni++) {
      int n = wx + ni * 16 + l15;
      bfv[ni] = *(const bf16x8*)&Bs[n * 32 + ((quad ^ (n & 3)) << 3)];
    }
#pragma unroll
    for (int mi = 0; mi < 4; mi++)
#pragma unroll
      for (int ni = 0; ni < 4; ni++)
        acc[mi][ni] = __builtin_amdgcn_mfma_f32_16x16x32_bf16(
            af[mi], bfv[ni], acc[mi][ni], 0, 0, 0);
  }

  const float* bias = z == 0 ? bq : (z == 1 ? bk : bv);
  bf16_t* outp      = z == 0 ? qo : (z == 1 ? ko : vo);
  const float scl   = (z == 0) ? QSCALE : 1.0f;
#pragma unroll
  for (int mi = 0; mi < 4; mi++) {
#pragma unroll
    for (int ni = 0; ni < 4; ni++) {
      const int nn = (n0g + wx + ni * 16 + l15) & (D_MODEL - 1);
      const float bvv = bias[nn];
      const int h = nn >> 6, d = nn & 63;
#pragma unroll
      for (int r = 0; r < 4; r++) {
        const int m = m0 + wy + mi * 16 + quad * 4 + r;
        const int b = m >> 11, srow = m & (S_LEN - 1);
        float v = (acc[mi][ni][r] + bvv) * scl;
        if (z < 2) {
          outp[((((size_t)(b * NHEAD + h) << 11) + srow) << 6) + d] = (bf16_t)v;
        } else {
          outp[((((size_t)(b * NHEAD + h) << 6) + d) << 11) + srow] = (bf16_t)v;
        }
      }
    }
  }
}

// ---------------------------------------------------------------------------
// LEGACY QKV (round-0 verified, 24 KB LDS, serial staging) — fallback when
// ws_size cannot hold the bf16 A buffer. Reads fp32 A directly.
// ---------------------------------------------------------------------------
__global__ __launch_bounds__(256, 3)
void qkv_legacy_kernel(const float* __restrict__ Qi, const float* __restrict__ Ki,
                       const float* __restrict__ Vi, const bf16_t* __restrict__ Wcat,
                       const float* __restrict__ bq, const float* __restrict__ bk,
                       const float* __restrict__ bv,
                       bf16_t* __restrict__ qo, bf16_t* __restrict__ ko,
                       bf16_t* __restrict__ vo)
{
  __shared__ float  Asf[128 * 32];
  __shared__ bf16_t Bs[128 * 32];

  const int L = blockIdx.x + 24 * blockIdx.y;
  const int j = (L >> 3) & 7;
  const int s = ((L >> 6) << 3) | (L & 7);
  const int z = s >> 6;
  const int n0g = (((z << 3) | j)) << 7;
  const int m0 = (s & 63) << 7;

  const float* A = z == 0 ? Qi : (z == 1 ? Ki : Vi);

  const int tid = threadIdx.x;
  const int lane = tid & 63;
  const int w = tid >> 6;
  const int l15 = lane & 15;
  const int quad = lane >> 4;
  const int wy = (w >> 1) << 6;
  const int wx = (w & 1) << 6;
  const int w64 = w << 6;

  floatx4 acc[4][4];
#pragma unroll
  for (int i = 0; i < 4; i++)
#pragma unroll
    for (int jj = 0; jj < 4; jj++)
#pragma unroll
      for (int r = 0; r < 4; r++) acc[i][jj][r] = 0.0f;

  for (int kt = 0; kt < 32; kt++) {
    const int k0 = kt << 5;
    __syncthreads();
#pragma unroll
    for (int p = 0; p < 2; p++) {
      int slot = p * 256 + w64 + lane;
      int row = slot >> 2;
      int kc = (slot & 3) ^ (row & 3);
      load_lds16(&Wcat[(size_t)(n0g + row) * D_MODEL + k0 + (kc << 3)],
                 &Bs[(size_t)(p * 256 + w64) << 3]);
    }
#pragma unroll
    for (int p = 0; p < 4; p++) {
      int sbase = (w << 8) + (p << 6);
      int slot = sbase + lane;
      int row = slot >> 3;
      int ca = (slot & 7) ^ (row & 7);
      load_lds16(&A[(size_t)(m0 + row) * D_MODEL + k0 + (ca << 2)],
                 &Asf[(size_t)sbase << 2]);
    }
    __syncthreads();

    bf16x8 af[4], bfv[4];
#pragma unroll
    for (int mi = 0; mi < 4; mi++) {
      const int m = wy + mi * 16 + l15;
      const int e = m & 7;
      floatx4 f0 = *(const floatx4*)&Asf[(m << 5) + ((((quad << 1))     ^ e) << 2)];
      floatx4 f1 = *(const floatx4*)&Asf[(m << 5) + ((((quad << 1) | 1) ^ e) << 2)];
      bf16x8 o;
      o[0] = (bf16_t)f0[0]; o[1] = (bf16_t)f0[1];
      o[2] = (bf16_t)f0[2]; o[3] = (bf16_t)f0[3];
      o[4] = (bf16_t)f1[0]; o[5] = (bf16_t)f1[1];
      o[6] = (bf16_t)f1[2]; o[7] = (bf16_t)f1[3];
      af[mi] = o;
    }
#pragma unroll
    for (int ni = 0; ni < 4; ni++) {
      int n = wx + ni * 16 + l15;
      bfv[ni] = *(const bf16x8*)&Bs[n * 32 + ((quad ^ (n & 3)) << 3)];
    }
#pragma unroll
    for (int mi = 0; mi < 4; mi++)
#pragma unroll
      for (int ni = 0; ni < 4; ni++)
        acc[mi][ni] = __builtin_amdgcn_mfma_f32_16x16x32_bf16(
            af[mi], bfv[ni], acc[mi][ni], 0, 0, 0);
  }

  const float* bias = z == 0 ? bq : (z == 1 ? bk : bv);
  bf16_t* outp      = z == 0 ? qo : (z == 1 ? ko : vo);
  const float scl   = (z == 0) ? QSCALE : 1.0f;
#pragma unroll
  for (int mi = 0; mi < 4; mi++) {
#pragma unroll
    for (int ni = 0; ni < 4; ni++) {
      const int nn = (n0g + wx + ni * 16 + l15) & (D_MODEL - 1);
      const float bvv = bias[nn];
      const int h = nn >> 6, d = nn & 63;
#pragma unroll
      for (int r = 0; r < 4; r++) {
        const int m = m0 + wy + mi * 16 + quad * 4 + r;
        const int b = m >> 11, srow = m & (S_LEN - 1);
        float v = (acc[mi][ni][r] + bvv) * scl;
        if (z < 2) {
          outp[((((size_t)(b * NHEAD + h) << 11) + srow) << 6) + d] = (bf16_t)v;
        } else {
          outp[((((size_t)(b * NHEAD + h) << 6) + d) << 11) + srow] = (bf16_t)v;
        }
      }
    }
  }
}

// ---------------------------------------------------------------------------
// Output GEMM: out = obuf(bf16) @ Wo + bo, fp32 out. Dual global_load_lds.
// (round-0 proven serial form; grid 512 = 2.0 exact rounds)
// ---------------------------------------------------------------------------
__global__ __launch_bounds__(256)
void out_gemm_kernel(const bf16_t* __restrict__ A, const bf16_t* __restrict__ Wt,
                     const float* __restrict__ bias, float* __restrict__ out)
{
  __shared__ bf16_t As[128 * 32];
  __shared__ bf16_t Bs[128 * 32];
  const int L = blockIdx.x + 8 * blockIdx.y;      // 0..511
  const int n0 = (((L >> 3) & 7)) << 7;
  const int m0 = ((((L >> 6) << 3) | (L & 7))) << 7;
  const int tid = threadIdx.x;
  const int lane = tid & 63;
  const int w = tid >> 6;
  const int l15 = lane & 15;
  const int quad = lane >> 4;
  const int wy = (w >> 1) << 6;
  const int wx = (w & 1) << 6;
  const int w64 = w << 6;

  floatx4 acc[4][4];
#pragma unroll
  for (int i = 0; i < 4; i++)
#pragma unroll
    for (int jj = 0; jj < 4; jj++)
#pragma unroll
      for (int r = 0; r < 4; r++) acc[i][jj][r] = 0.0f;

  for (int kt = 0; kt < 32; kt++) {
    const int k0 = kt << 5;
    __syncthreads();
#pragma unroll
    for (int p = 0; p < 2; p++) {
      int slot = p * 256 + w64 + lane;
      int row = slot >> 2;
      int kc = (slot & 3) ^ (row & 3);
      load_lds16(&A[(size_t)(m0 + row) * D_MODEL + k0 + (kc << 3)],
                 &As[(size_t)(p * 256 + w64) << 3]);
      load_lds16(&Wt[(size_t)(n0 + row) * D_MODEL + k0 + (kc << 3)],
                 &Bs[(size_t)(p * 256 + w64) << 3]);
    }
    __syncthreads();

    bf16x8 af[4], bfv[4];
#pragma unroll
    for (int mi = 0; mi < 4; mi++) {
      int m = wy + mi * 16 + l15;
      af[mi] = *(const bf16x8*)&As[m * 32 + ((quad ^ (m & 3)) << 3)];
    }
#pragma unroll
    for (int ni = 0; ni < 4; ni++) {
      int n = wx + ni * 16 + l15;
      bfv[ni] = *(const bf16x8*)&Bs[n * 32 + ((quad ^ (n & 3)) << 3)];
    }
#pragma unroll
    for (int mi = 0; mi < 4; mi++)
#pragma unroll
      for (int ni = 0; ni < 4; ni++)
        acc[mi][ni] = __builtin_amdgcn_mfma_f32_16x16x32_bf16(
            af[mi], bfv[ni], acc[mi][ni], 0, 0, 0);
  }

#pragma unroll
  for (int mi = 0; mi < 4; mi++) {
#pragma unroll
    for (int ni = 0; ni < 4; ni++) {
      const int nbase = n0 + wx + ni * 16 + l15;
      const float bv = bias[nbase];
#pragma unroll
      for (int r = 0; r < 4; r++) {
        const int m = m0 + wy + mi * 16 + quad * 4 + r;
        out[((size_t)m << 10) + nbase] = acc[mi][ni][r] + bv;
      }
    }
  }
}

// ---------------------------------------------------------------------------
// Causal flash attention, S^T formulation, BALANCED pairing (r5-verified).
// XCD-clustering remap + setprio + defer-max (round-4 verified).
// ---------------------------------------------------------------------------
__global__ __launch_bounds__(256, 4)
void attn_kernel(const bf16_t* __restrict__ qp, const bf16_t* __restrict__ kp,
                 const bf16_t* __restrict__ vtp, bf16_t* __restrict__ ob)
{
  __shared__ bf16_t Kt0[64 * 64];
  __shared__ bf16_t Kt1[64 * 64];
  __shared__ bf16_t Vt0[64 * 64];
  __shared__ bf16_t Vt1[64 * 64];

  const int lin = blockIdx.x + (blockIdx.y << 4);   // 0..1023
  const int pair = (lin >> 3) & 15;                 // 0..15
  const int bh = (lin & 7) | ((lin >> 7) << 3);     // 0..63
  const int tid = threadIdx.x;
  const int w = tid >> 6;
  const int lane = tid & 63;
  const int l15 = lane & 15;
  const int quad = lane >> 4;

  const bf16_t* Qh = qp + ((size_t)bh << 17);
  const bf16_t* Kh = kp + ((size_t)bh << 17);
  const bf16_t* Vh = vtp + ((size_t)bh << 17);   // [64][2048]
  const int b = bh >> 4, h = bh & 15;

  auto stage = [&](int k0s, bf16_t* dK, bf16_t* dV) {
#pragma unroll
    for (int p = 0; p < 2; p++) {
      const int sbase = (w << 7) + (p << 6);
      const int slot = sbase + lane;
      const int row = slot >> 3;
      const int c = (slot & 7) ^ (row & 7);
      load_lds16(&Kh[((size_t)(k0s + row) << 6) + (c << 3)], &dK[sbase << 3]);
      load_lds16(&Vh[((size_t)row << 11) + k0s + (c << 3)], &dV[sbase << 3]);
    }
  };

  int par = 0;   // global tile-counter parity: current buffer index

  auto phase = [&](int qt, bool prefetch_next_phase) {
    const int q0 = qt << 6;
    const int qbase = q0 + (w << 4);       // wave's 16 q-rows
    const int nkb = qt + 1;

    bf16x8 qf[2];
#pragma unroll
    for (int ks = 0; ks < 2; ks++)
      qf[ks] = *(const bf16x8*)&Qh[(size_t)(qbase + l15) * DK +
                                   ks * 32 + (quad << 3)];

    floatx4 acc_o[4];
    float m_i = -1e30f, l_i = 0.0f;
#pragma unroll
    for (int nd = 0; nd < 4; nd++)
#pragma unroll
      for (int r = 0; r < 4; r++) acc_o[nd][r] = 0.0f;

    for (int kb = 0; kb < nkb; kb++) {
      const int k0 = kb << 6;
      __syncthreads();   // drains this tile's gll (issued one body ago)

      const bf16_t* cK = par ? Kt1 : Kt0;
      const bf16_t* cV = par ? Vt1 : Vt0;
      bf16_t* nK = par ? Kt0 : Kt1;
      bf16_t* nV = par ? Vt0 : Vt1;

      if (kb + 1 < nkb)             stage((kb + 1) << 6, nK, nV);
      else if (prefetch_next_phase) stage(0, nK, nV);

      bf16x8 bk[2][4];
#pragma unroll
      for (int ks = 0; ks < 2; ks++)
#pragma unroll
        for (int ni = 0; ni < 4; ni++) {
          const int row = ni * 16 + l15;
          const int cp = ((ks << 2) + quad) ^ (row & 7);
          bk[ks][ni] = *(const bf16x8*)&cK[(row << 6) + (cp << 3)];
        }

      floatx4 st[4];
#pragma unroll
      for (int ni = 0; ni < 4; ni++)
#pragma unroll
        for (int r = 0; r < 4; r++) st[ni][r] = 0.0f;
      __builtin_amdgcn_s_setprio(1);
#pragma unroll
      for (int ks = 0; ks < 2; ks++)
#pragma unroll
        for (int ni = 0; ni < 4; ni++)
          st[ni] = __builtin_amdgcn_mfma_f32_16x16x32_bf16(
              bk[ks][ni], qf[ks], st[ni], 0, 0, 0);
      __builtin_amdgcn_s_setprio(0);

      if (k0 + 63 > qbase) {
        const int qrow = qbase + l15;
#pragma unroll
        for (int ni = 0; ni < 4; ni++) {
          const int keyb = k0 + ni * 16 + quad * 4;
#pragma unroll
          for (int r = 0; r < 4; r++)
            if (keyb + r > qrow) st[ni][r] = -1e30f;
        }
      }

      float v = st[0][0];
#pragma unroll
      for (int ni = 0; ni < 4; ni++)
#pragma unroll
        for (int r = 0; r < 4; r++) v = fmaxf(v, st[ni][r]);
      v = fmaxf(v, __shfl_xor(v, 16));
      v = fmaxf(v, __shfl_xor(v, 32));

      // Defer-max (T13): skip rescale when tile max doesn't grow past THR.
      if (!__all(v <= m_i + 5.0f)) {
        const float mn = fmaxf(m_i, v);
        const float alpha = __builtin_amdgcn_exp2f(m_i - mn);
        m_i = mn;
        l_i *= alpha;
#pragma unroll
        for (int r = 0; r < 4; r++) {
          float ab = bperm_f((quad * 4 + r) << 2, alpha);
#pragma unroll
          for (int nd = 0; nd < 4; nd++) acc_o[nd][r] *= ab;
        }
      }

      unsigned pd[4][2];
      float ssum = 0.0f;
#pragma unroll
      for (int c = 0; c < 4; c++)
#pragma unroll
        for (int hh = 0; hh < 2; hh++) {
          float p0 = __builtin_amdgcn_exp2f(st[c][2 * hh]     - m_i);
          float p1 = __builtin_amdgcn_exp2f(st[c][2 * hh + 1] - m_i);
          ssum += p0 + p1;
          pd[c][hh] = pack_bf16(p0, p1);
        }
      ssum += __shfl_xor(ssum, 16);
      ssum += __shfl_xor(ssum, 32);
      l_i += ssum;

      union AV { unsigned u[4]; bf16x8 v; };
      AV av[2];
#pragma unroll
      for (int ks = 0; ks < 2; ks++)
#pragma unroll
        for (int i = 0; i < 4; i++) {
          const int addr = ((((2 * quad + (i >> 1)) & 3) << 4) | l15) << 2;
          int lo = __builtin_amdgcn_ds_bpermute(addr, (int)pd[ks * 2][i & 1]);
          int hi = __builtin_amdgcn_ds_bpermute(addr, (int)pd[ks * 2 + 1][i & 1]);
          av[ks].u[i] = (unsigned)(quad >= 2 ? hi : lo);
        }

#pragma unroll
      for (int ks = 0; ks < 2; ks++) {
        bf16x8 bvv[4];
#pragma unroll
        for (int nd = 0; nd < 4; nd++) {
          const int row = nd * 16 + l15;
          const int cp = ((ks << 2) + quad) ^ (row & 7);
          bvv[nd] = *(const bf16x8*)&cV[(row << 6) + (cp << 3)];
        }
        __builtin_amdgcn_s_setprio(1);
#pragma unroll
        for (int nd = 0; nd < 4; nd++)
          acc_o[nd] = __builtin_amdgcn_mfma_f32_16x16x32_bf16(
              av[ks].v, bvv[nd], acc_o[nd], 0, 0, 0);
        __builtin_amdgcn_s_setprio(0);
      }

      par ^= 1;
    }

    const float inv = 1.0f / l_i;
#pragma unroll
    for (int r = 0; r < 4; r++) {
      const float linv = bperm_f((quad * 4 + r) << 2, inv);
      const int sRow = qbase + quad * 4 + r;
#pragma unroll
      for (int nd = 0; nd < 4; nd++) {
        const int d = nd * 16 + l15;
        ob[(((size_t)(b * S_LEN + sRow)) << 10) + h * 64 + d] =
            (bf16_t)(acc_o[nd][r] * linv);
      }
    }
  };

  stage(0, Kt0, Vt0);            // tile 0 of phase A into buffer 0
  phase(31 - pair, true);        // big tile first; prefetch B's tile 0 at seam
  phase(pair, false);            // total bodies = (32-p) + (p+1) = 33, uniform
}

// ---------------------------------------------------------------------------
extern "C" void kernel_launch(void* const* d_in, const int* in_sizes, int n_in,
                              void* d_out, int out_size, void* d_ws, size_t ws_size,
                              hipStream_t stream)
{
  (void)in_sizes; (void)n_in; (void)out_size;
  const float* Q  = (const float*)d_in[0];
  const float* K  = (const float*)d_in[1];
  const float* V  = (const float*)d_in[2];
  const float* Wq = (const float*)d_in[4];
  const float* bq = (const float*)d_in[5];
  const float* Wk = (const float*)d_in[6];
  const float* bk = (const float*)d_in[7];
  const float* Wv = (const float*)d_in[8];
  const float* bv = (const float*)d_in[9];
  const float* Wo = (const float*)d_in[10];
  const float* bo = (const float*)d_in[11];
  float* out = (float*)d_out;

  const size_t NELT = (size_t)MROWS * D_MODEL;        // 8 Mi elements
  const size_t WELT = (size_t)D_MODEL * D_MODEL;      // 1 Mi elements

  // Layout (104 MB): qp|kp|vtp (48MB) | weights (8MB) | abf (48MB).
  // obuf ALIASES abf (abf dead after qkv; obuf born after).
  const size_t need_new = (3 * NELT + 4 * WELT + 3 * NELT) * sizeof(bf16_t);

  bf16_t* qp   = (bf16_t*)d_ws;
  bf16_t* kp   = qp + NELT;
  bf16_t* vtp  = kp + NELT;
  bf16_t* wqt  = vtp + NELT;
  bf16_t* wkt  = wqt + WELT;
  bf16_t* wvt  = wkt + WELT;
  bf16_t* wot  = wvt + WELT;
  bf16_t* abf  = wot + WELT;       // [3][8192][1024] bf16 (new path only)
  bf16_t* obuf = abf;              // alias: lives in abf's first 16MB

  dim3 blk(256);
  transpose_w_kernel<<<dim3(16, 16, 4), blk, 0, stream>>>(
      Wq, Wk, Wv, Wo, wqt, wkt, wvt, wot);

  if (ws_size >= need_new) {
    convert_a_kernel<<<dim3(MROWS * D_MODEL / (256 * 8), 3), blk, 0, stream>>>(
        Q, K, V, abf);
    qkv_bf16_kernel<<<dim3(3 * D_MODEL / 128, MROWS / 128), blk, 0, stream>>>(
        abf, wqt, bq, bk, bv, qp, kp, vtp);
  } else {
    // Fallback (72 MB, round-0 verified): obuf sits where abf would start.
    qkv_legacy_kernel<<<dim3(3 * D_MODEL / 128, MROWS / 128), blk, 0, stream>>>(
        Q, K, V, wqt, bq, bk, bv, qp, kp, vtp);
  }

  attn_kernel<<<dim3(16, BATCH * NHEAD), blk, 0, stream>>>(qp, kp, vtp, obuf);

  out_gemm_kernel<<<dim3(D_MODEL / 128, MROWS / 128), blk, 0, stream>>>(
      obuf, wot, bo, out);
}